// Round 15
// baseline (137.316 us; speedup 1.0000x reference)
//
#include <hip/hip_runtime.h>

#define D_MODEL 1024
#define NH 16
#define DK 64
#define BB 2
#define SS 2048
#define M_TOT (BB*SS)

typedef float f32x4 __attribute__((ext_vector_type(4)));
typedef float f32x16 __attribute__((ext_vector_type(16)));
typedef __bf16 bf16x8 __attribute__((ext_vector_type(8)));
typedef unsigned int u32;

// 0.125 (1/sqrt(dk)) * log2(e): folds softmax scaling + base-2 exp into Q
#define QSCALE 0.1803368801f
#define DEFER_THR 11.5416f   // 8 * log2(e)

__device__ __forceinline__ unsigned short f2bf(float f){
  unsigned int u = __float_as_uint(f);
  unsigned int r = (u + 0x7fffu + ((u >> 16) & 1u)) >> 16;
  return (unsigned short)r;
}

__device__ __forceinline__ void gload_lds16(const void* g, void* l){
  __builtin_amdgcn_global_load_lds((const __attribute__((address_space(1))) void*)g,
                                   (__attribute__((address_space(3))) void*)l,
                                   16, 0, 0);
}

// exchange 32-lane halves: x = {lo: a.lo, hi: b.lo}, y = {lo: a.hi, hi: b.hi}
__device__ __forceinline__ void swap_half(u32 a, u32 b, int hi, u32& x, u32& y){
#if __has_builtin(__builtin_amdgcn_permlane32_swap)
  typedef unsigned int uint2v __attribute__((ext_vector_type(2)));
  uint2v r = __builtin_amdgcn_permlane32_swap(a, b, false, false);
  x = r.x; y = r.y;
#else
  u32 as = __shfl_xor(a, 32);
  u32 bs = __shfl_xor(b, 32);
  x = hi ? bs : a;
  y = hi ? b  : as;
#endif
}

// ---------------- fp32 -> bf16 convert: q,k,v in one dispatch ----------------
__global__ __launch_bounds__(256) void cvt3_bf16(const float* __restrict__ q,
                                                 const float* __restrict__ k,
                                                 const float* __restrict__ v,
                                                 unsigned short* __restrict__ qb,
                                                 unsigned short* __restrict__ kb,
                                                 unsigned short* __restrict__ vb){
  const int which = blockIdx.y;
  const float* in = (which == 0) ? q : (which == 1) ? k : v;
  unsigned short* out = (which == 0) ? qb : (which == 1) ? kb : vb;
  int i = blockIdx.x * 256 + threadIdx.x;
  float4 f = ((const float4*)in)[i];
  ushort4 o;
  o.x = f2bf(f.x); o.y = f2bf(f.y); o.z = f2bf(f.z); o.w = f2bf(f.w);
  ((ushort4*)out)[i] = o;
}

// ------------- fp32 [K][N] -> bf16 [N][K] transpose-convert, 4 mats -------------
__global__ __launch_bounds__(256) void transpose_cvt4(const float* __restrict__ wq,
                                                      const float* __restrict__ wk,
                                                      const float* __restrict__ wv,
                                                      const float* __restrict__ wo,
                                                      unsigned short* __restrict__ WqkvT,
                                                      unsigned short* __restrict__ woT){
  __shared__ float tile[64][65];
  const int which = blockIdx.z;
  const float* w = (which == 0) ? wq : (which == 1) ? wk : (which == 2) ? wv : wo;
  unsigned short* wt = (which == 3) ? woT : (WqkvT + (size_t)which * 1024 * 1024);
  const int N = D_MODEL;
  const int bx = blockIdx.x * 64;
  const int by = blockIdx.y * 64;
  const int t = threadIdx.x;
  #pragma unroll
  for (int i = 0; i < 16; ++i){
    int idx = t + i * 256;
    int r = idx >> 6, c = idx & 63;
    tile[r][c] = w[(size_t)(by + r) * N + bx + c];
  }
  __syncthreads();
  #pragma unroll
  for (int i = 0; i < 16; ++i){
    int idx = t + i * 256;
    int r = idx >> 6, c = idx & 63;
    wt[(size_t)(bx + r) * N + by + c] = f2bf(tile[c][r]);
  }
}

// ---------------- fused QKV projection GEMM ----------------
// seg 0 -> Qh scatter (pre-scaled by QSCALE), seg 1 -> Kh scatter,
// seg 2 -> VhT transposed store.
__global__ __launch_bounds__(256) void gemm_qkv(const unsigned short* __restrict__ Aq,
                                                const unsigned short* __restrict__ Ak,
                                                const unsigned short* __restrict__ Av,
                                                const unsigned short* __restrict__ WT,
                                                unsigned short* __restrict__ Qh,
                                                unsigned short* __restrict__ Kh,
                                                unsigned short* __restrict__ VhT){
  __shared__ unsigned short Al[2][128 * 32];
  __shared__ unsigned short Bl[2][128 * 32];
  const int tid = threadIdx.x;
  const int wid = tid >> 6, lane = tid & 63;
  const int lr = lane & 15, lg = lane >> 4;
  const int wm = wid >> 1, wn = wid & 1;
  const int bm = blockIdx.x, bn = blockIdx.y;
  const int seg = bn >> 3;
  const unsigned short* A = (seg == 0) ? Aq : (seg == 1) ? Ak : Av;
  const int K = D_MODEL;

  f32x4 acc[4][4];
  #pragma unroll
  for (int i = 0; i < 4; ++i)
    #pragma unroll
    for (int j = 0; j < 4; ++j)
      acc[i][j] = (f32x4){0.f, 0.f, 0.f, 0.f};

  auto stage = [&](int buf, int kt){
    #pragma unroll
    for (int r = 0; r < 2; ++r){
      int vt = tid + r * 256;
      int row = vt >> 2, c8 = (vt & 3) * 8;
      gload_lds16(A  + (size_t)(bm * 128 + row) * K + kt * 32 + c8,
                  &Al[buf][(wid << 9) + r * 2048]);
      gload_lds16(WT + (size_t)(bn * 128 + row) * K + kt * 32 + c8,
                  &Bl[buf][(wid << 9) + r * 2048]);
    }
  };

  stage(0, 0);
  int cur = 0;
  for (int kt = 0; kt < 32; ++kt){
    __syncthreads();
    if (kt + 1 < 32) stage(cur ^ 1, kt + 1);
    bf16x8 af[4], bfr[4];
    #pragma unroll
    for (int i = 0; i < 4; ++i)
      af[i] = *(const bf16x8*)&Al[cur][(wm * 64 + i * 16 + lr) * 32 + lg * 8];
    #pragma unroll
    for (int j = 0; j < 4; ++j)
      bfr[j] = *(const bf16x8*)&Bl[cur][(wn * 64 + j * 16 + lr) * 32 + lg * 8];
    #pragma unroll
    for (int i = 0; i < 4; ++i)
      #pragma unroll
      for (int j = 0; j < 4; ++j)
        acc[i][j] = __builtin_amdgcn_mfma_f32_16x16x32_bf16(af[i], bfr[j], acc[i][j], 0, 0, 0);
    cur ^= 1;
  }

  if (seg < 2){
    unsigned short* O = (seg == 0) ? Qh : Kh;
    const float sc = (seg == 0) ? QSCALE : 1.0f;
    #pragma unroll
    for (int i = 0; i < 4; ++i){
      int row0 = bm * 128 + wm * 64 + i * 16 + lg * 4;
      #pragma unroll
      for (int j = 0; j < 4; ++j){
        int colseg = (bn & 7) * 128 + wn * 64 + j * 16 + lr;
        int h = colseg >> 6, dk = colseg & 63;
        #pragma unroll
        for (int p = 0; p < 4; ++p){
          int rowm = row0 + p;
          int b = rowm >> 11, s = rowm & 2047;
          O[((size_t)(b * NH + h) * SS + s) * DK + dk] = f2bf(acc[i][j][p] * sc);
        }
      }
    }
  } else {
    #pragma unroll
    for (int i = 0; i < 4; ++i){
      int row0 = bm * 128 + wm * 64 + i * 16 + lg * 4;
      int b = row0 >> 11, s = row0 & 2047;
      #pragma unroll
      for (int j = 0; j < 4; ++j){
        int colseg = (bn & 7) * 128 + wn * 64 + j * 16 + lr;
        int h = colseg >> 6, dk = colseg & 63;
        ushort4 o4;
        o4.x = f2bf(acc[i][j][0]); o4.y = f2bf(acc[i][j][1]);
        o4.z = f2bf(acc[i][j][2]); o4.w = f2bf(acc[i][j][3]);
        *(ushort4*)&VhT[((size_t)(b * NH + h) * DK + dk) * SS + s] = o4;
      }
    }
  }
}

// ---------------- output projection GEMM (BM=64 for occupancy) ----------------
__global__ __launch_bounds__(256) void gemm_o64(const unsigned short* __restrict__ A,
                                                const unsigned short* __restrict__ Bt,
                                                float* __restrict__ O){
  __shared__ unsigned short Al[2][64 * 32];
  __shared__ unsigned short Bl[2][128 * 32];
  const int tid = threadIdx.x;
  const int wid = tid >> 6, lane = tid & 63;
  const int lr = lane & 15, lg = lane >> 4;
  const int wm = wid >> 1, wn = wid & 1;
  const int bm = blockIdx.x, bn = blockIdx.y;
  const int K = D_MODEL;

  f32x4 acc[2][4];
  #pragma unroll
  for (int i = 0; i < 2; ++i)
    #pragma unroll
    for (int j = 0; j < 4; ++j)
      acc[i][j] = (f32x4){0.f, 0.f, 0.f, 0.f};

  auto stage = [&](int buf, int kt){
    {
      int row = tid >> 2, c8 = (tid & 3) * 8;
      gload_lds16(A + (size_t)(bm * 64 + row) * K + kt * 32 + c8,
                  &Al[buf][wid << 9]);
    }
    #pragma unroll
    for (int r = 0; r < 2; ++r){
      int vt = tid + r * 256;
      int row = vt >> 2, c8 = (vt & 3) * 8;
      gload_lds16(Bt + (size_t)(bn * 128 + row) * K + kt * 32 + c8,
                  &Bl[buf][(wid << 9) + r * 2048]);
    }
  };

  stage(0, 0);
  int cur = 0;
  for (int kt = 0; kt < 32; ++kt){
    __syncthreads();
    if (kt + 1 < 32) stage(cur ^ 1, kt + 1);
    bf16x8 af[2], bfr[4];
    #pragma unroll
    for (int i = 0; i < 2; ++i)
      af[i] = *(const bf16x8*)&Al[cur][(wm * 32 + i * 16 + lr) * 32 + lg * 8];
    #pragma unroll
    for (int j = 0; j < 4; ++j)
      bfr[j] = *(const bf16x8*)&Bl[cur][(wn * 64 + j * 16 + lr) * 32 + lg * 8];
    #pragma unroll
    for (int i = 0; i < 2; ++i)
      #pragma unroll
      for (int j = 0; j < 4; ++j)
        acc[i][j] = __builtin_amdgcn_mfma_f32_16x16x32_bf16(af[i], bfr[j], acc[i][j], 0, 0, 0);
    cur ^= 1;
  }

  #pragma unroll
  for (int i = 0; i < 2; ++i){
    int row0 = bm * 64 + wm * 32 + i * 16 + lg * 4;
    #pragma unroll
    for (int j = 0; j < 4; ++j){
      int col = bn * 128 + wn * 64 + j * 16 + lr;
      #pragma unroll
      for (int p = 0; p < 4; ++p)
        O[(size_t)(row0 + p) * D_MODEL + col] = acc[i][j][p];
    }
  }
}

// ---------------- causal flash attention: barrier-free 1-wave blocks ----------------
// Block = ONE wave (64 thr) owning a 32-row q-tile. Grid (bh=32, 64), qt = 63-y
// (LPT, dynamic backfill). Per 64-key step: wave stages its own K (8KB) + V^T
// (8KB) tile into private LDS via gload_lds (coalesced, wave-uniform base).
// EXPLICIT wave-local fences (round-14 lesson: compiler does NOT track the
// ds_read <- DMA-write dependency of global_load_lds):
//   after staging:  s_waitcnt vmcnt(0) + sched_barrier  (DMA landed before reads)
//   before staging: s_waitcnt lgkmcnt(0)                (reads retired before overwrite)
// No __syncthreads anywhere. Body = r12-proven compute.
__global__ __launch_bounds__(64) void attn_kernel(const unsigned short* __restrict__ Qh,
                                                  const unsigned short* __restrict__ Kh,
                                                  const unsigned short* __restrict__ VhT,
                                                  unsigned short* __restrict__ Oc){
  __shared__ unsigned short SL[2][4096];      // K tile | V tile, 8 KB each
  const int bh = blockIdx.x;                  // bh%8 -> XCD stickiness
  const int qt = 63 - blockIdx.y;             // 32-row q-tile index, LPT order
  const int lane = threadIdx.x & 63;
  const int ln = lane & 31, hi = lane >> 5;
  const int b = bh >> 4, h = bh & 15;
  const size_t kvbase = (size_t)bh * SS * DK;
  const int q0 = qt * 32;
  const int Tw = qt;                          // diagonal 32-key tile index
  const int NS = (qt + 2) >> 1;               // 64-key steps

  const unsigned short* qp = Qh + kvbase + (size_t)(q0 + ln) * DK + hi * 8;
  bf16x8 qbv[4];
  #pragma unroll
  for (int c = 0; c < 4; ++c) qbv[c] = *(const bf16x8*)(qp + c * 16);

  f32x16 oa0 = {0,0,0,0,0,0,0,0,0,0,0,0,0,0,0,0};
  f32x16 oa1 = {0,0,0,0,0,0,0,0,0,0,0,0,0,0,0,0};
  float m = -1e30f, ls = 0.f;

  #pragma unroll 1
  for (int s = 0; s < NS; ++s){
    const int k0 = s * 64;
    // ---- WAR fence: prior rounds' ds_reads retired before DMA overwrite ----
    asm volatile("s_waitcnt lgkmcnt(0)" ::: "memory");
    // ---- per-wave staging: K [64k][64d], V^T [64d][64s], swizzled source ----
    #pragma unroll
    for (int i = 0; i < 8; ++i){
      const int row = i * 8 + (lane >> 3);
      const int slot = (lane & 7) ^ (row & 7);
      gload_lds16(Kh  + kvbase + (size_t)(k0 + row) * DK + slot * 8, &SL[0][i * 512]);
      gload_lds16(VhT + kvbase + (size_t)row * SS + k0 + slot * 8,   &SL[1][i * 512]);
    }
    // ---- RAW fence: DMA writes landed before any ds_read ----
    asm volatile("s_waitcnt vmcnt(0)" ::: "memory");
    __builtin_amdgcn_sched_barrier(0);
    const unsigned short* Kb = SL[0];
    const unsigned short* Vb = SL[1];

    // S^T (log2 domain) for key sub-tiles a (k0..+31) / b (k0+32..+63)
    f32x16 sta = {0,0,0,0,0,0,0,0,0,0,0,0,0,0,0,0};
    f32x16 stb = {0,0,0,0,0,0,0,0,0,0,0,0,0,0,0,0};
    __builtin_amdgcn_s_setprio(1);
    #pragma unroll
    for (int c = 0; c < 4; ++c){
      const int po = ((c * 2 + hi) ^ (ln & 7)) * 8;
      bf16x8 kfa = *(const bf16x8*)&Kb[ln * 64 + po];
      bf16x8 kfb = *(const bf16x8*)&Kb[(32 + ln) * 64 + po];
      sta = __builtin_amdgcn_mfma_f32_32x32x16_bf16(kfa, qbv[c], sta, 0, 0, 0);
      stb = __builtin_amdgcn_mfma_f32_32x32x16_bf16(kfb, qbv[c], stb, 0, 0, 0);
    }
    __builtin_amdgcn_s_setprio(0);

    // causal mask: 32-key tiles ta=2s, tb=2s+1 vs diag Tw
    const int ta = 2 * s, tb = 2 * s + 1;
    if (tb == Tw){
      #pragma unroll
      for (int rr = 0; rr < 16; ++rr){
        int kg = (rr & 3) + 8 * (rr >> 2) + 4 * hi;
        if (kg > ln) stb[rr] = -1e30f;
      }
    } else if (ta == Tw){
      #pragma unroll
      for (int rr = 0; rr < 16; ++rr){
        int kg = (rr & 3) + 8 * (rr >> 2) + 4 * hi;
        if (kg > ln) sta[rr] = -1e30f;
        stb[rr] = -1e30f;
      }
    }

    // tree max
    float tm[8];
    #pragma unroll
    for (int i = 0; i < 8; ++i)
      tm[i] = fmaxf(fmaxf(sta[2*i], sta[2*i+1]), fmaxf(stb[2*i], stb[2*i+1]));
    float mx = fmaxf(fmaxf(fmaxf(tm[0], tm[1]), fmaxf(tm[2], tm[3])),
                     fmaxf(fmaxf(tm[4], tm[5]), fmaxf(tm[6], tm[7])));
    mx = fmaxf(mx, __shfl_xor(mx, 32));

    // defer-max rescale
    if (__any(mx > m + DEFER_THR)){
      const float mn = fmaxf(m, mx);
      const float fac = __builtin_amdgcn_exp2f(m - mn);
      m = mn;
      ls *= fac;
      #pragma unroll
      for (int rr = 0; rr < 16; ++rr){ oa0[rr] *= fac; oa1[rr] *= fac; }
    }

    // P = exp2(st - m), tree sum
    #pragma unroll
    for (int rr = 0; rr < 16; ++rr){
      sta[rr] = __builtin_amdgcn_exp2f(sta[rr] - m);
      stb[rr] = __builtin_amdgcn_exp2f(stb[rr] - m);
    }
    float sm[8];
    #pragma unroll
    for (int i = 0; i < 8; ++i)
      sm[i] = (sta[2*i] + sta[2*i+1]) + (stb[2*i] + stb[2*i+1]);
    float rsum = ((sm[0] + sm[1]) + (sm[2] + sm[3])) + ((sm[4] + sm[5]) + (sm[6] + sm[7]));
    rsum += __shfl_xor(rsum, 32);
    ls += rsum;

    // P^T -> bf16 B-fragments
    u32 ca[8], cb[8];
    #pragma unroll
    for (int i = 0; i < 8; ++i){
      asm("v_cvt_pk_bf16_f32 %0, %1, %2" : "=v"(ca[i]) : "v"(sta[2*i]), "v"(sta[2*i+1]));
      asm("v_cvt_pk_bf16_f32 %0, %1, %2" : "=v"(cb[i]) : "v"(stb[2*i]), "v"(stb[2*i+1]));
    }
    u32 w0[4], w1[4], w2[4], w3[4];
    swap_half(ca[0], ca[2], hi, w0[0], w0[2]);
    swap_half(ca[1], ca[3], hi, w0[1], w0[3]);
    swap_half(ca[4], ca[6], hi, w1[0], w1[2]);
    swap_half(ca[5], ca[7], hi, w1[1], w1[3]);
    swap_half(cb[0], cb[2], hi, w2[0], w2[2]);
    swap_half(cb[1], cb[3], hi, w2[1], w2[3]);
    swap_half(cb[4], cb[6], hi, w3[0], w3[2]);
    swap_half(cb[5], cb[7], hi, w3[1], w3[3]);
    bf16x8 pf[4];
    __builtin_memcpy(&pf[0], w0, 16);
    __builtin_memcpy(&pf[1], w1, 16);
    __builtin_memcpy(&pf[2], w2, 16);
    __builtin_memcpy(&pf[3], w3, 16);

    // O^T += V^T * P^T
    __builtin_amdgcn_s_setprio(1);
    #pragma unroll
    for (int ks = 0; ks < 4; ++ks){
      const int po = ((ks * 2 + hi) ^ (ln & 7)) * 8;
      bf16x8 v0 = *(const bf16x8*)&Vb[ln * 64 + po];
      bf16x8 v1 = *(const bf16x8*)&Vb[(32 + ln) * 64 + po];
      oa0 = __builtin_amdgcn_mfma_f32_32x32x16_bf16(v0, pf[ks], oa0, 0, 0, 0);
      oa1 = __builtin_amdgcn_mfma_f32_32x32x16_bf16(v1, pf[ks], oa1, 0, 0, 0);
    }
    __builtin_amdgcn_s_setprio(0);
  }

  // ---- epilogue: direct normalized store ----
  const float inv = 1.0f / ls;
  const size_t rowbase = ((size_t)b * SS + q0 + ln) * D_MODEL + h * DK;
  #pragma unroll
  for (int g = 0; g < 4; ++g){
    ushort4 o4;
    o4.x = f2bf(oa0[4*g + 0] * inv); o4.y = f2bf(oa0[4*g + 1] * inv);
    o4.z = f2bf(oa0[4*g + 2] * inv); o4.w = f2bf(oa0[4*g + 3] * inv);
    *(ushort4*)&Oc[rowbase + 8*g + 4*hi] = o4;
  }
  #pragma unroll
  for (int g = 0; g < 4; ++g){
    ushort4 o4;
    o4.x = f2bf(oa1[4*g + 0] * inv); o4.y = f2bf(oa1[4*g + 1] * inv);
    o4.z = f2bf(oa1[4*g + 2] * inv); o4.w = f2bf(oa1[4*g + 3] * inv);
    *(ushort4*)&Oc[rowbase + 32 + 8*g + 4*hi] = o4;
  }
}

extern "C" void kernel_launch(void* const* d_in, const int* in_sizes, int n_in,
                              void* d_out, int out_size, void* d_ws, size_t ws_size,
                              hipStream_t stream){
  const float* q  = (const float*)d_in[0];
  const float* k  = (const float*)d_in[1];
  const float* v  = (const float*)d_in[2];
  // d_in[3]: causal mask (deterministic tril) — hardcoded in attn kernel
  const float* wq = (const float*)d_in[4];
  const float* wk = (const float*)d_in[5];
  const float* wv = (const float*)d_in[6];
  const float* wo = (const float*)d_in[7];
  float* out = (float*)d_out;

  char* ws = (char*)d_ws;
  const size_t MB = 1024 * 1024;
  unsigned short* qb     = (unsigned short*)(ws + 0 * MB);
  unsigned short* kb     = (unsigned short*)(ws + 8 * MB);
  unsigned short* vb     = (unsigned short*)(ws + 16 * MB);
  unsigned short* WqkvT  = (unsigned short*)(ws + 24 * MB);   // 6 MB
  unsigned short* woT    = (unsigned short*)(ws + 30 * MB);
  unsigned short* Qh     = (unsigned short*)(ws + 32 * MB);
  unsigned short* Kh     = (unsigned short*)(ws + 40 * MB);
  unsigned short* VhT    = (unsigned short*)(ws + 48 * MB);
  unsigned short* attnb  = (unsigned short*)(ws + 56 * MB);

  const int n4 = (M_TOT * D_MODEL) / 4;   // per tensor
  dim3 gc(n4 / 256, 3);
  cvt3_bf16<<<gc, 256, 0, stream>>>(q, k, v, qb, kb, vb);

  dim3 tg(16, 16, 4);
  transpose_cvt4<<<tg, 256, 0, stream>>>(wq, wk, wv, wo, WqkvT, woT);

  dim3 gqkv(M_TOT / 128, 3 * D_MODEL / 128);   // (32, 24) = 768 blocks
  gemm_qkv<<<gqkv, 256, 0, stream>>>(qb, kb, vb, WqkvT, Qh, Kh, VhT);

  dim3 ga(BB * NH, SS / 32);                   // (32 bh, 64 qt): 2048 1-wave blocks
  attn_kernel<<<ga, 64, 0, stream>>>(Qh, Kh, VhT, attnb);

  dim3 go(M_TOT / 64, D_MODEL / 128);          // (64, 8) = 512 blocks
  gemm_o64<<<go, 256, 0, stream>>>(attnb, woT, out);
}

// Round 16
// 136.507 us; speedup vs baseline: 1.0059x; 1.0059x over previous
//
#include <hip/hip_runtime.h>

#define D_MODEL 1024
#define NH 16
#define DK 64
#define BB 2
#define SS 2048
#define M_TOT (BB*SS)

typedef float f32x4 __attribute__((ext_vector_type(4)));
typedef float f32x16 __attribute__((ext_vector_type(16)));
typedef __bf16 bf16x8 __attribute__((ext_vector_type(8)));
typedef unsigned int u32;

// 0.125 (1/sqrt(dk)) * log2(e): folds softmax scaling + base-2 exp into Q
#define QSCALE 0.1803368801f
#define DEFER_THR 11.5416f   // 8 * log2(e)

__device__ __forceinline__ unsigned short f2bf(float f){
  unsigned int u = __float_as_uint(f);
  unsigned int r = (u + 0x7fffu + ((u >> 16) & 1u)) >> 16;
  return (unsigned short)r;
}

__device__ __forceinline__ void gload_lds16(const void* g, void* l){
  __builtin_amdgcn_global_load_lds((const __attribute__((address_space(1))) void*)g,
                                   (__attribute__((address_space(3))) void*)l,
                                   16, 0, 0);
}

// exchange 32-lane halves: x = {lo: a.lo, hi: b.lo}, y = {lo: a.hi, hi: b.hi}
__device__ __forceinline__ void swap_half(u32 a, u32 b, int hi, u32& x, u32& y){
#if __has_builtin(__builtin_amdgcn_permlane32_swap)
  typedef unsigned int uint2v __attribute__((ext_vector_type(2)));
  uint2v r = __builtin_amdgcn_permlane32_swap(a, b, false, false);
  x = r.x; y = r.y;
#else
  u32 as = __shfl_xor(a, 32);
  u32 bs = __shfl_xor(b, 32);
  x = hi ? bs : a;
  y = hi ? b  : as;
#endif
}

// ---------------- fp32 -> bf16 convert: q,k,v in one dispatch ----------------
__global__ __launch_bounds__(256) void cvt3_bf16(const float* __restrict__ q,
                                                 const float* __restrict__ k,
                                                 const float* __restrict__ v,
                                                 unsigned short* __restrict__ qb,
                                                 unsigned short* __restrict__ kb,
                                                 unsigned short* __restrict__ vb){
  const int which = blockIdx.y;
  const float* in = (which == 0) ? q : (which == 1) ? k : v;
  unsigned short* out = (which == 0) ? qb : (which == 1) ? kb : vb;
  int i = blockIdx.x * 256 + threadIdx.x;
  float4 f = ((const float4*)in)[i];
  ushort4 o;
  o.x = f2bf(f.x); o.y = f2bf(f.y); o.z = f2bf(f.z); o.w = f2bf(f.w);
  ((ushort4*)out)[i] = o;
}

// ------------- fp32 [K][N] -> bf16 [N][K] transpose-convert, 4 mats -------------
__global__ __launch_bounds__(256) void transpose_cvt4(const float* __restrict__ wq,
                                                      const float* __restrict__ wk,
                                                      const float* __restrict__ wv,
                                                      const float* __restrict__ wo,
                                                      unsigned short* __restrict__ WqkvT,
                                                      unsigned short* __restrict__ woT){
  __shared__ float tile[64][65];
  const int which = blockIdx.z;
  const float* w = (which == 0) ? wq : (which == 1) ? wk : (which == 2) ? wv : wo;
  unsigned short* wt = (which == 3) ? woT : (WqkvT + (size_t)which * 1024 * 1024);
  const int N = D_MODEL;
  const int bx = blockIdx.x * 64;
  const int by = blockIdx.y * 64;
  const int t = threadIdx.x;
  #pragma unroll
  for (int i = 0; i < 16; ++i){
    int idx = t + i * 256;
    int r = idx >> 6, c = idx & 63;
    tile[r][c] = w[(size_t)(by + r) * N + bx + c];
  }
  __syncthreads();
  #pragma unroll
  for (int i = 0; i < 16; ++i){
    int idx = t + i * 256;
    int r = idx >> 6, c = idx & 63;
    wt[(size_t)(bx + r) * N + by + c] = f2bf(tile[c][r]);
  }
}

// ---------------- fused QKV projection GEMM ----------------
// seg 0 -> Qh scatter (pre-scaled by QSCALE), seg 1 -> Kh scatter,
// seg 2 -> VhT transposed store.
__global__ __launch_bounds__(256) void gemm_qkv(const unsigned short* __restrict__ Aq,
                                                const unsigned short* __restrict__ Ak,
                                                const unsigned short* __restrict__ Av,
                                                const unsigned short* __restrict__ WT,
                                                unsigned short* __restrict__ Qh,
                                                unsigned short* __restrict__ Kh,
                                                unsigned short* __restrict__ VhT){
  __shared__ unsigned short Al[2][128 * 32];
  __shared__ unsigned short Bl[2][128 * 32];
  const int tid = threadIdx.x;
  const int wid = tid >> 6, lane = tid & 63;
  const int lr = lane & 15, lg = lane >> 4;
  const int wm = wid >> 1, wn = wid & 1;
  const int bm = blockIdx.x, bn = blockIdx.y;
  const int seg = bn >> 3;
  const unsigned short* A = (seg == 0) ? Aq : (seg == 1) ? Ak : Av;
  const int K = D_MODEL;

  f32x4 acc[4][4];
  #pragma unroll
  for (int i = 0; i < 4; ++i)
    #pragma unroll
    for (int j = 0; j < 4; ++j)
      acc[i][j] = (f32x4){0.f, 0.f, 0.f, 0.f};

  auto stage = [&](int buf, int kt){
    #pragma unroll
    for (int r = 0; r < 2; ++r){
      int vt = tid + r * 256;
      int row = vt >> 2, c8 = (vt & 3) * 8;
      gload_lds16(A  + (size_t)(bm * 128 + row) * K + kt * 32 + c8,
                  &Al[buf][(wid << 9) + r * 2048]);
      gload_lds16(WT + (size_t)(bn * 128 + row) * K + kt * 32 + c8,
                  &Bl[buf][(wid << 9) + r * 2048]);
    }
  };

  stage(0, 0);
  int cur = 0;
  for (int kt = 0; kt < 32; ++kt){
    __syncthreads();
    if (kt + 1 < 32) stage(cur ^ 1, kt + 1);
    bf16x8 af[4], bfr[4];
    #pragma unroll
    for (int i = 0; i < 4; ++i)
      af[i] = *(const bf16x8*)&Al[cur][(wm * 64 + i * 16 + lr) * 32 + lg * 8];
    #pragma unroll
    for (int j = 0; j < 4; ++j)
      bfr[j] = *(const bf16x8*)&Bl[cur][(wn * 64 + j * 16 + lr) * 32 + lg * 8];
    #pragma unroll
    for (int i = 0; i < 4; ++i)
      #pragma unroll
      for (int j = 0; j < 4; ++j)
        acc[i][j] = __builtin_amdgcn_mfma_f32_16x16x32_bf16(af[i], bfr[j], acc[i][j], 0, 0, 0);
    cur ^= 1;
  }

  if (seg < 2){
    unsigned short* O = (seg == 0) ? Qh : Kh;
    const float sc = (seg == 0) ? QSCALE : 1.0f;
    #pragma unroll
    for (int i = 0; i < 4; ++i){
      int row0 = bm * 128 + wm * 64 + i * 16 + lg * 4;
      #pragma unroll
      for (int j = 0; j < 4; ++j){
        int colseg = (bn & 7) * 128 + wn * 64 + j * 16 + lr;
        int h = colseg >> 6, dk = colseg & 63;
        #pragma unroll
        for (int p = 0; p < 4; ++p){
          int rowm = row0 + p;
          int b = rowm >> 11, s = rowm & 2047;
          O[((size_t)(b * NH + h) * SS + s) * DK + dk] = f2bf(acc[i][j][p] * sc);
        }
      }
    }
  } else {
    #pragma unroll
    for (int i = 0; i < 4; ++i){
      int row0 = bm * 128 + wm * 64 + i * 16 + lg * 4;
      int b = row0 >> 11, s = row0 & 2047;
      #pragma unroll
      for (int j = 0; j < 4; ++j){
        int colseg = (bn & 7) * 128 + wn * 64 + j * 16 + lr;
        int h = colseg >> 6, dk = colseg & 63;
        ushort4 o4;
        o4.x = f2bf(acc[i][j][0]); o4.y = f2bf(acc[i][j][1]);
        o4.z = f2bf(acc[i][j][2]); o4.w = f2bf(acc[i][j][3]);
        *(ushort4*)&VhT[((size_t)(b * NH + h) * DK + dk) * SS + s] = o4;
      }
    }
  }
}

// ---------------- output projection GEMM (BM=64 for occupancy) ----------------
__global__ __launch_bounds__(256) void gemm_o64(const unsigned short* __restrict__ A,
                                                const unsigned short* __restrict__ Bt,
                                                float* __restrict__ O){
  __shared__ unsigned short Al[2][64 * 32];
  __shared__ unsigned short Bl[2][128 * 32];
  const int tid = threadIdx.x;
  const int wid = tid >> 6, lane = tid & 63;
  const int lr = lane & 15, lg = lane >> 4;
  const int wm = wid >> 1, wn = wid & 1;
  const int bm = blockIdx.x, bn = blockIdx.y;
  const int K = D_MODEL;

  f32x4 acc[2][4];
  #pragma unroll
  for (int i = 0; i < 2; ++i)
    #pragma unroll
    for (int j = 0; j < 4; ++j)
      acc[i][j] = (f32x4){0.f, 0.f, 0.f, 0.f};

  auto stage = [&](int buf, int kt){
    {
      int row = tid >> 2, c8 = (tid & 3) * 8;
      gload_lds16(A + (size_t)(bm * 64 + row) * K + kt * 32 + c8,
                  &Al[buf][wid << 9]);
    }
    #pragma unroll
    for (int r = 0; r < 2; ++r){
      int vt = tid + r * 256;
      int row = vt >> 2, c8 = (vt & 3) * 8;
      gload_lds16(Bt + (size_t)(bn * 128 + row) * K + kt * 32 + c8,
                  &Bl[buf][(wid << 9) + r * 2048]);
    }
  };

  stage(0, 0);
  int cur = 0;
  for (int kt = 0; kt < 32; ++kt){
    __syncthreads();
    if (kt + 1 < 32) stage(cur ^ 1, kt + 1);
    bf16x8 af[2], bfr[4];
    #pragma unroll
    for (int i = 0; i < 2; ++i)
      af[i] = *(const bf16x8*)&Al[cur][(wm * 32 + i * 16 + lr) * 32 + lg * 8];
    #pragma unroll
    for (int j = 0; j < 4; ++j)
      bfr[j] = *(const bf16x8*)&Bl[cur][(wn * 64 + j * 16 + lr) * 32 + lg * 8];
    #pragma unroll
    for (int i = 0; i < 2; ++i)
      #pragma unroll
      for (int j = 0; j < 4; ++j)
        acc[i][j] = __builtin_amdgcn_mfma_f32_16x16x32_bf16(af[i], bfr[j], acc[i][j], 0, 0, 0);
    cur ^= 1;
  }

  #pragma unroll
  for (int i = 0; i < 2; ++i){
    int row0 = bm * 64 + wm * 32 + i * 16 + lg * 4;
    #pragma unroll
    for (int j = 0; j < 4; ++j){
      int col = bn * 128 + wn * 64 + j * 16 + lr;
      #pragma unroll
      for (int p = 0; p < 4; ++p)
        O[(size_t)(row0 + p) * D_MODEL + col] = acc[i][j][p];
    }
  }
}

// ---------------- causal flash attention: 1-wave blocks, wave-local dbuf ----------------
// Block = ONE wave owning a 32-row q-tile; grid (bh=32, 64), qt=63-y (LPT).
// Wave-local LDS double buffer + counted vmcnt (T4):
//   prologue: drain Q loads (vmcnt(0) baseline), issue stage(buf0,t=0)
//   iter t:   lgkmcnt(0) [WAR] -> issue stage(buf^1,t+1) -> vmcnt(16)
//             [buf t landed; t+1 flies under compute] -> sched_barrier -> compute
//   tail:     vmcnt(0). No __syncthreads. Exactly 16 gload_lds per stage; no
//             other VMEM in the loop, so the count is exact.
__global__ __launch_bounds__(64) void attn_kernel(const unsigned short* __restrict__ Qh,
                                                  const unsigned short* __restrict__ Kh,
                                                  const unsigned short* __restrict__ VhT,
                                                  unsigned short* __restrict__ Oc){
  __shared__ unsigned short SL[2][2][4096];   // [buf][K|V][8KB] = 32 KB
  const int bh = blockIdx.x;                  // bh%8 -> XCD stickiness
  const int qt = 63 - blockIdx.y;             // 32-row q-tile index, LPT order
  const int lane = threadIdx.x & 63;
  const int ln = lane & 31, hi = lane >> 5;
  const int b = bh >> 4, h = bh & 15;
  const size_t kvbase = (size_t)bh * SS * DK;
  const int q0 = qt * 32;
  const int Tw = qt;                          // diagonal 32-key tile index
  const int NS = (qt + 2) >> 1;               // 64-key steps

  const unsigned short* qp = Qh + kvbase + (size_t)(q0 + ln) * DK + hi * 8;
  bf16x8 qbv[4];
  #pragma unroll
  for (int c = 0; c < 4; ++c) qbv[c] = *(const bf16x8*)(qp + c * 16);
  // baseline the VMEM counter: Q loads drained before counted staging begins
  asm volatile("s_waitcnt vmcnt(0)" ::: "memory");

  f32x16 oa0 = {0,0,0,0,0,0,0,0,0,0,0,0,0,0,0,0};
  f32x16 oa1 = {0,0,0,0,0,0,0,0,0,0,0,0,0,0,0,0};
  float m = -1e30f, ls = 0.f;

  const int lrow8 = lane >> 3;
  const int lcol  = lane & 7;

  auto stage_issue = [&](int buf, int s){
    const int k0 = s * 64;
    #pragma unroll
    for (int i = 0; i < 8; ++i){
      const int row = i * 8 + lrow8;
      const int slot = lcol ^ (row & 7);
      gload_lds16(Kh  + kvbase + (size_t)(k0 + row) * DK + slot * 8, &SL[buf][0][i * 512]);
      gload_lds16(VhT + kvbase + (size_t)row * SS + k0 + slot * 8,   &SL[buf][1][i * 512]);
    }
  };

  stage_issue(0, 0);                          // 16 loads in flight

  #pragma unroll 1
  for (int s = 0; s < NS; ++s){
    const int cur = s & 1;
    // WAR: prior round's ds_reads retired before DMA overwrites buf cur^1
    asm volatile("s_waitcnt lgkmcnt(0)" ::: "memory");
    if (s + 1 < NS){
      stage_issue(cur ^ 1, s + 1);            // 16 more in flight (32 total)
      asm volatile("s_waitcnt vmcnt(16)" ::: "memory");   // buf[cur] landed
    } else {
      asm volatile("s_waitcnt vmcnt(0)" ::: "memory");
    }
    __builtin_amdgcn_sched_barrier(0);
    const unsigned short* Kb = SL[cur][0];
    const unsigned short* Vb = SL[cur][1];
    const int k0 = s * 64; (void)k0;

    // S^T (log2 domain) for key sub-tiles a (64s..+31) / b (+32..+63)
    f32x16 sta = {0,0,0,0,0,0,0,0,0,0,0,0,0,0,0,0};
    f32x16 stb = {0,0,0,0,0,0,0,0,0,0,0,0,0,0,0,0};
    __builtin_amdgcn_s_setprio(1);
    #pragma unroll
    for (int c = 0; c < 4; ++c){
      const int po = ((c * 2 + hi) ^ (ln & 7)) * 8;
      bf16x8 kfa = *(const bf16x8*)&Kb[ln * 64 + po];
      bf16x8 kfb = *(const bf16x8*)&Kb[(32 + ln) * 64 + po];
      sta = __builtin_amdgcn_mfma_f32_32x32x16_bf16(kfa, qbv[c], sta, 0, 0, 0);
      stb = __builtin_amdgcn_mfma_f32_32x32x16_bf16(kfb, qbv[c], stb, 0, 0, 0);
    }
    __builtin_amdgcn_s_setprio(0);

    // causal mask: 32-key tiles ta=2s, tb=2s+1 vs diag Tw
    const int ta = 2 * s, tb = 2 * s + 1;
    if (tb == Tw){
      #pragma unroll
      for (int rr = 0; rr < 16; ++rr){
        int kg = (rr & 3) + 8 * (rr >> 2) + 4 * hi;
        if (kg > ln) stb[rr] = -1e30f;
      }
    } else if (ta == Tw){
      #pragma unroll
      for (int rr = 0; rr < 16; ++rr){
        int kg = (rr & 3) + 8 * (rr >> 2) + 4 * hi;
        if (kg > ln) sta[rr] = -1e30f;
        stb[rr] = -1e30f;
      }
    }

    // tree max
    float tm[8];
    #pragma unroll
    for (int i = 0; i < 8; ++i)
      tm[i] = fmaxf(fmaxf(sta[2*i], sta[2*i+1]), fmaxf(stb[2*i], stb[2*i+1]));
    float mx = fmaxf(fmaxf(fmaxf(tm[0], tm[1]), fmaxf(tm[2], tm[3])),
                     fmaxf(fmaxf(tm[4], tm[5]), fmaxf(tm[6], tm[7])));
    mx = fmaxf(mx, __shfl_xor(mx, 32));

    // defer-max rescale
    if (__any(mx > m + DEFER_THR)){
      const float mn = fmaxf(m, mx);
      const float fac = __builtin_amdgcn_exp2f(m - mn);
      m = mn;
      ls *= fac;
      #pragma unroll
      for (int rr = 0; rr < 16; ++rr){ oa0[rr] *= fac; oa1[rr] *= fac; }
    }

    // P = exp2(st - m), tree sum
    #pragma unroll
    for (int rr = 0; rr < 16; ++rr){
      sta[rr] = __builtin_amdgcn_exp2f(sta[rr] - m);
      stb[rr] = __builtin_amdgcn_exp2f(stb[rr] - m);
    }
    float sm[8];
    #pragma unroll
    for (int i = 0; i < 8; ++i)
      sm[i] = (sta[2*i] + sta[2*i+1]) + (stb[2*i] + stb[2*i+1]);
    float rsum = ((sm[0] + sm[1]) + (sm[2] + sm[3])) + ((sm[4] + sm[5]) + (sm[6] + sm[7]));
    rsum += __shfl_xor(rsum, 32);
    ls += rsum;

    // P^T -> bf16 B-fragments
    u32 ca[8], cb[8];
    #pragma unroll
    for (int i = 0; i < 8; ++i){
      asm("v_cvt_pk_bf16_f32 %0, %1, %2" : "=v"(ca[i]) : "v"(sta[2*i]), "v"(sta[2*i+1]));
      asm("v_cvt_pk_bf16_f32 %0, %1, %2" : "=v"(cb[i]) : "v"(stb[2*i]), "v"(stb[2*i+1]));
    }
    u32 w0[4], w1[4], w2[4], w3[4];
    swap_half(ca[0], ca[2], hi, w0[0], w0[2]);
    swap_half(ca[1], ca[3], hi, w0[1], w0[3]);
    swap_half(ca[4], ca[6], hi, w1[0], w1[2]);
    swap_half(ca[5], ca[7], hi, w1[1], w1[3]);
    swap_half(cb[0], cb[2], hi, w2[0], w2[2]);
    swap_half(cb[1], cb[3], hi, w2[1], w2[3]);
    swap_half(cb[4], cb[6], hi, w3[0], w3[2]);
    swap_half(cb[5], cb[7], hi, w3[1], w3[3]);
    bf16x8 pf[4];
    __builtin_memcpy(&pf[0], w0, 16);
    __builtin_memcpy(&pf[1], w1, 16);
    __builtin_memcpy(&pf[2], w2, 16);
    __builtin_memcpy(&pf[3], w3, 16);

    // O^T += V^T * P^T
    __builtin_amdgcn_s_setprio(1);
    #pragma unroll
    for (int ks = 0; ks < 4; ++ks){
      const int po = ((ks * 2 + hi) ^ (ln & 7)) * 8;
      bf16x8 v0 = *(const bf16x8*)&Vb[ln * 64 + po];
      bf16x8 v1 = *(const bf16x8*)&Vb[(32 + ln) * 64 + po];
      oa0 = __builtin_amdgcn_mfma_f32_32x32x16_bf16(v0, pf[ks], oa0, 0, 0, 0);
      oa1 = __builtin_amdgcn_mfma_f32_32x32x16_bf16(v1, pf[ks], oa1, 0, 0, 0);
    }
    __builtin_amdgcn_s_setprio(0);
  }

  // ---- epilogue: direct normalized store ----
  const float inv = 1.0f / ls;
  const size_t rowbase = ((size_t)b * SS + q0 + ln) * D_MODEL + h * DK;
  #pragma unroll
  for (int g = 0; g < 4; ++g){
    ushort4 o4;
    o4.x = f2bf(oa0[4*g + 0] * inv); o4.y = f2bf(oa0[4*g + 1] * inv);
    o4.z = f2bf(oa0[4*g + 2] * inv); o4.w = f2bf(oa0[4*g + 3] * inv);
    *(ushort4*)&Oc[rowbase + 8*g + 4*hi] = o4;
  }
  #pragma unroll
  for (int g = 0; g < 4; ++g){
    ushort4 o4;
    o4.x = f2bf(oa1[4*g + 0] * inv); o4.y = f2bf(oa1[4*g + 1] * inv);
    o4.z = f2bf(oa1[4*g + 2] * inv); o4.w = f2bf(oa1[4*g + 3] * inv);
    *(ushort4*)&Oc[rowbase + 32 + 8*g + 4*hi] = o4;
  }
}

extern "C" void kernel_launch(void* const* d_in, const int* in_sizes, int n_in,
                              void* d_out, int out_size, void* d_ws, size_t ws_size,
                              hipStream_t stream){
  const float* q  = (const float*)d_in[0];
  const float* k  = (const float*)d_in[1];
  const float* v  = (const float*)d_in[2];
  // d_in[3]: causal mask (deterministic tril) — hardcoded in attn kernel
  const float* wq = (const float*)d_in[4];
  const float* wk = (const float*)d_in[5];
  const float* wv = (const float*)d_in[6];
  const float* wo = (const float*)d_in[7];
  float* out = (float*)d_out;

  char* ws = (char*)d_ws;
  const size_t MB = 1024 * 1024;
  unsigned short* qb     = (unsigned short*)(ws + 0 * MB);
  unsigned short* kb     = (unsigned short*)(ws + 8 * MB);
  unsigned short* vb     = (unsigned short*)(ws + 16 * MB);
  unsigned short* WqkvT  = (unsigned short*)(ws + 24 * MB);   // 6 MB
  unsigned short* woT    = (unsigned short*)(ws + 30 * MB);
  unsigned short* Qh     = (unsigned short*)(ws + 32 * MB);
  unsigned short* Kh     = (unsigned short*)(ws + 40 * MB);
  unsigned short* VhT    = (unsigned short*)(ws + 48 * MB);
  unsigned short* attnb  = (unsigned short*)(ws + 56 * MB);

  const int n4 = (M_TOT * D_MODEL) / 4;   // per tensor
  dim3 gc(n4 / 256, 3);
  cvt3_bf16<<<gc, 256, 0, stream>>>(q, k, v, qb, kb, vb);

  dim3 tg(16, 16, 4);
  transpose_cvt4<<<tg, 256, 0, stream>>>(wq, wk, wv, wo, WqkvT, woT);

  dim3 gqkv(M_TOT / 128, 3 * D_MODEL / 128);   // (32, 24) = 768 blocks
  gemm_qkv<<<gqkv, 256, 0, stream>>>(qb, kb, vb, WqkvT, Qh, Kh, VhT);

  dim3 ga(BB * NH, SS / 32);                   // (32 bh, 64 qt): 2048 1-wave blocks
  attn_kernel<<<ga, 64, 0, stream>>>(Qh, Kh, VhT, attnb);

  dim3 go(M_TOT / 64, D_MODEL / 128);          // (64, 8) = 512 blocks
  gemm_o64<<<go, 256, 0, stream>>>(attnb, woT, out);
}

// Round 17
// 118.744 us; speedup vs baseline: 1.1564x; 1.1496x over previous
//
#include <hip/hip_runtime.h>

#define D_MODEL 1024
#define NH 16
#define DK 64
#define BB 2
#define SS 2048
#define M_TOT (BB*SS)

typedef float f32x4 __attribute__((ext_vector_type(4)));
typedef float f32x16 __attribute__((ext_vector_type(16)));
typedef __bf16 bf16x8 __attribute__((ext_vector_type(8)));
typedef unsigned int u32;

// 0.125 (1/sqrt(dk)) * log2(e): folds softmax scaling + base-2 exp into Q
#define QSCALE 0.1803368801f
#define DEFER_THR 11.5416f   // 8 * log2(e)

__device__ __forceinline__ unsigned short f2bf(float f){
  unsigned int u = __float_as_uint(f);
  unsigned int r = (u + 0x7fffu + ((u >> 16) & 1u)) >> 16;
  return (unsigned short)r;
}

__device__ __forceinline__ void gload_lds16(const void* g, void* l){
  __builtin_amdgcn_global_load_lds((const __attribute__((address_space(1))) void*)g,
                                   (__attribute__((address_space(3))) void*)l,
                                   16, 0, 0);
}

// exchange 32-lane halves: x = {lo: a.lo, hi: b.lo}, y = {lo: a.hi, hi: b.hi}
__device__ __forceinline__ void swap_half(u32 a, u32 b, int hi, u32& x, u32& y){
#if __has_builtin(__builtin_amdgcn_permlane32_swap)
  typedef unsigned int uint2v __attribute__((ext_vector_type(2)));
  uint2v r = __builtin_amdgcn_permlane32_swap(a, b, false, false);
  x = r.x; y = r.y;
#else
  u32 as = __shfl_xor(a, 32);
  u32 bs = __shfl_xor(b, 32);
  x = hi ? bs : a;
  y = hi ? b  : as;
#endif
}

// ------------- fp32 [K][N] -> bf16 [N][K] transpose-convert, 4 mats -------------
__global__ __launch_bounds__(256) void transpose_cvt4(const float* __restrict__ wq,
                                                      const float* __restrict__ wk,
                                                      const float* __restrict__ wv,
                                                      const float* __restrict__ wo,
                                                      unsigned short* __restrict__ WqkvT,
                                                      unsigned short* __restrict__ woT){
  __shared__ float tile[64][65];
  const int which = blockIdx.z;
  const float* w = (which == 0) ? wq : (which == 1) ? wk : (which == 2) ? wv : wo;
  unsigned short* wt = (which == 3) ? woT : (WqkvT + (size_t)which * 1024 * 1024);
  const int N = D_MODEL;
  const int bx = blockIdx.x * 64;
  const int by = blockIdx.y * 64;
  const int t = threadIdx.x;
  #pragma unroll
  for (int i = 0; i < 16; ++i){
    int idx = t + i * 256;
    int r = idx >> 6, c = idx & 63;
    tile[r][c] = w[(size_t)(by + r) * N + bx + c];
  }
  __syncthreads();
  #pragma unroll
  for (int i = 0; i < 16; ++i){
    int idx = t + i * 256;
    int r = idx >> 6, c = idx & 63;
    wt[(size_t)(bx + r) * N + by + c] = f2bf(tile[c][r]);
  }
}

// ---------------- fused QKV projection GEMM, fp32 A inputs (fused convert) ----------------
// A (q/k/v, fp32) staged raw into LDS via gload_lds with XOR-swizzled source
// (rule #21 both-sides: 128B fp32 rows would 16-way conflict otherwise);
// converted to bf16 fragments at read time via v_cvt_pk_bf16_f32.
// seg 0 -> Qh scatter (pre-scaled by QSCALE), seg 1 -> Kh scatter,
// seg 2 -> VhT transposed store.
__global__ __launch_bounds__(256) void gemm_qkv(const float* __restrict__ Aq,
                                                const float* __restrict__ Ak,
                                                const float* __restrict__ Av,
                                                const unsigned short* __restrict__ WT,
                                                unsigned short* __restrict__ Qh,
                                                unsigned short* __restrict__ Kh,
                                                unsigned short* __restrict__ VhT){
  __shared__ float          Af[2][128 * 32];   // 32 KB, swizzled [row][slot^(row&7)]
  __shared__ unsigned short Bl[2][128 * 32];   // 16 KB, linear (proven layout)
  const int tid = threadIdx.x;
  const int wid = tid >> 6, lane = tid & 63;
  const int lr = lane & 15, lg = lane >> 4;
  const int wm = wid >> 1, wn = wid & 1;
  const int bm = blockIdx.x, bn = blockIdx.y;
  const int seg = bn >> 3;
  const float* A = (seg == 0) ? Aq : (seg == 1) ? Ak : Av;
  const int K = D_MODEL;

  f32x4 acc[4][4];
  #pragma unroll
  for (int i = 0; i < 4; ++i)
    #pragma unroll
    for (int j = 0; j < 4; ++j)
      acc[i][j] = (f32x4){0.f, 0.f, 0.f, 0.f};

  const int lr8 = lane >> 3;        // 0..7: row-within-8
  const int lc8 = lane & 7;         // 0..7: physical 16B slot
  const int ls8 = lc8 ^ lr8;        // logical slot (swizzle inverse)

  auto stage = [&](int buf, int kt){
    // A: fp32, 4 wave-instrs/wave x 4 waves = 16 x 1KB = 128 rows x 128B
    #pragma unroll
    for (int i = 0; i < 4; ++i){
      const int g = wid * 4 + i;                    // 0..15
      const int r = g * 8 + lr8;                    // row 0..127
      gload_lds16(A + (size_t)(bm * 128 + r) * K + kt * 32 + ls8 * 4,
                  &Af[buf][g * 256]);               // wave-uniform base (floats)
    }
    // B: bf16, unchanged proven pattern
    #pragma unroll
    for (int rr = 0; rr < 2; ++rr){
      int vt = tid + rr * 256;
      int row = vt >> 2, c8 = (vt & 3) * 8;
      gload_lds16(WT + (size_t)(bn * 128 + row) * K + kt * 32 + c8,
                  &Bl[buf][(wid << 9) + rr * 2048]);
    }
  };

  stage(0, 0);
  int cur = 0;
  for (int kt = 0; kt < 32; ++kt){
    __syncthreads();                 // drains vmcnt for stage(cur)
    if (kt + 1 < 32) stage(cur ^ 1, kt + 1);
    bf16x8 af[4], bfr[4];
    const int rs = lr & 7;
    #pragma unroll
    for (int i = 0; i < 4; ++i){
      const int row = wm * 64 + i * 16 + lr;
      f32x4 a0 = *(const f32x4*)&Af[cur][row * 32 + (((2 * lg)     ^ rs) * 4)];
      f32x4 a1 = *(const f32x4*)&Af[cur][row * 32 + (((2 * lg + 1) ^ rs) * 4)];
      u32 cc[4];
      asm("v_cvt_pk_bf16_f32 %0, %1, %2" : "=v"(cc[0]) : "v"(a0[0]), "v"(a0[1]));
      asm("v_cvt_pk_bf16_f32 %0, %1, %2" : "=v"(cc[1]) : "v"(a0[2]), "v"(a0[3]));
      asm("v_cvt_pk_bf16_f32 %0, %1, %2" : "=v"(cc[2]) : "v"(a1[0]), "v"(a1[1]));
      asm("v_cvt_pk_bf16_f32 %0, %1, %2" : "=v"(cc[3]) : "v"(a1[2]), "v"(a1[3]));
      __builtin_memcpy(&af[i], cc, 16);
    }
    #pragma unroll
    for (int j = 0; j < 4; ++j)
      bfr[j] = *(const bf16x8*)&Bl[cur][(wn * 64 + j * 16 + lr) * 32 + lg * 8];
    #pragma unroll
    for (int i = 0; i < 4; ++i)
      #pragma unroll
      for (int j = 0; j < 4; ++j)
        acc[i][j] = __builtin_amdgcn_mfma_f32_16x16x32_bf16(af[i], bfr[j], acc[i][j], 0, 0, 0);
    cur ^= 1;
  }

  if (seg < 2){
    unsigned short* O = (seg == 0) ? Qh : Kh;
    const float sc = (seg == 0) ? QSCALE : 1.0f;
    #pragma unroll
    for (int i = 0; i < 4; ++i){
      int row0 = bm * 128 + wm * 64 + i * 16 + lg * 4;
      #pragma unroll
      for (int j = 0; j < 4; ++j){
        int colseg = (bn & 7) * 128 + wn * 64 + j * 16 + lr;
        int h = colseg >> 6, dk = colseg & 63;
        #pragma unroll
        for (int p = 0; p < 4; ++p){
          int rowm = row0 + p;
          int b = rowm >> 11, s = rowm & 2047;
          O[((size_t)(b * NH + h) * SS + s) * DK + dk] = f2bf(acc[i][j][p] * sc);
        }
      }
    }
  } else {
    #pragma unroll
    for (int i = 0; i < 4; ++i){
      int row0 = bm * 128 + wm * 64 + i * 16 + lg * 4;
      int b = row0 >> 11, s = row0 & 2047;
      #pragma unroll
      for (int j = 0; j < 4; ++j){
        int colseg = (bn & 7) * 128 + wn * 64 + j * 16 + lr;
        int h = colseg >> 6, dk = colseg & 63;
        ushort4 o4;
        o4.x = f2bf(acc[i][j][0]); o4.y = f2bf(acc[i][j][1]);
        o4.z = f2bf(acc[i][j][2]); o4.w = f2bf(acc[i][j][3]);
        *(ushort4*)&VhT[((size_t)(b * NH + h) * DK + dk) * SS + s] = o4;
      }
    }
  }
}

// ---------------- output projection GEMM (BM=64 for occupancy) ----------------
__global__ __launch_bounds__(256) void gemm_o64(const unsigned short* __restrict__ A,
                                                const unsigned short* __restrict__ Bt,
                                                float* __restrict__ O){
  __shared__ unsigned short Al[2][64 * 32];
  __shared__ unsigned short Bl[2][128 * 32];
  const int tid = threadIdx.x;
  const int wid = tid >> 6, lane = tid & 63;
  const int lr = lane & 15, lg = lane >> 4;
  const int wm = wid >> 1, wn = wid & 1;
  const int bm = blockIdx.x, bn = blockIdx.y;
  const int K = D_MODEL;

  f32x4 acc[2][4];
  #pragma unroll
  for (int i = 0; i < 2; ++i)
    #pragma unroll
    for (int j = 0; j < 4; ++j)
      acc[i][j] = (f32x4){0.f, 0.f, 0.f, 0.f};

  auto stage = [&](int buf, int kt){
    {
      int row = tid >> 2, c8 = (tid & 3) * 8;
      gload_lds16(A + (size_t)(bm * 64 + row) * K + kt * 32 + c8,
                  &Al[buf][wid << 9]);
    }
    #pragma unroll
    for (int r = 0; r < 2; ++r){
      int vt = tid + r * 256;
      int row = vt >> 2, c8 = (vt & 3) * 8;
      gload_lds16(Bt + (size_t)(bn * 128 + row) * K + kt * 32 + c8,
                  &Bl[buf][(wid << 9) + r * 2048]);
    }
  };

  stage(0, 0);
  int cur = 0;
  for (int kt = 0; kt < 32; ++kt){
    __syncthreads();
    if (kt + 1 < 32) stage(cur ^ 1, kt + 1);
    bf16x8 af[2], bfr[4];
    #pragma unroll
    for (int i = 0; i < 2; ++i)
      af[i] = *(const bf16x8*)&Al[cur][(wm * 32 + i * 16 + lr) * 32 + lg * 8];
    #pragma unroll
    for (int j = 0; j < 4; ++j)
      bfr[j] = *(const bf16x8*)&Bl[cur][(wn * 64 + j * 16 + lr) * 32 + lg * 8];
    #pragma unroll
    for (int i = 0; i < 2; ++i)
      #pragma unroll
      for (int j = 0; j < 4; ++j)
        acc[i][j] = __builtin_amdgcn_mfma_f32_16x16x32_bf16(af[i], bfr[j], acc[i][j], 0, 0, 0);
    cur ^= 1;
  }

  #pragma unroll
  for (int i = 0; i < 2; ++i){
    int row0 = bm * 64 + wm * 32 + i * 16 + lg * 4;
    #pragma unroll
    for (int j = 0; j < 4; ++j){
      int col = bn * 128 + wn * 64 + j * 16 + lr;
      #pragma unroll
      for (int p = 0; p < 4; ++p)
        O[(size_t)(row0 + p) * D_MODEL + col] = acc[i][j][p];
    }
  }
}

// ---------------- causal flash attention: 4-wave split-K + fold + LDS dbuf ----------------
// (round-12 proven kernel, 51.0 us) Grid (bh=32, px=16). Block processes
// qblk = px then 31-px (~17.5 rounds flat). m97 stage-ahead order:
// __syncthreads(); stage(next -> buf^1); compute(buf). 64 KB LDS dbuf.
__global__ __launch_bounds__(256) void attn_kernel(const unsigned short* __restrict__ Qh,
                                                   const unsigned short* __restrict__ Kh,
                                                   const unsigned short* __restrict__ VhT,
                                                   unsigned short* __restrict__ Oc){
  __shared__ unsigned short SL[2][4][4096];   // [buf][KA|VA|KB|VB][8KB], 64 KB
  const int bh = blockIdx.x;                  // bh%8 -> XCD stickiness
  const int px = blockIdx.y;                  // 0..15
  const int tid = threadIdx.x, wid = tid >> 6, lane = tid & 63;
  const int ln = lane & 31, hi = lane >> 5;
  const int qh = wid & 1, pp = wid >> 1;      // q-half, K-parity
  const int b = bh >> 4, h = bh & 15;
  const size_t kvbase = (size_t)bh * SS * DK;

  #pragma unroll 1
  for (int segq = 0; segq < 2; ++segq){
    const int qblk = segq ? (31 - px) : px;
    const int q0 = qblk * 64 + qh * 32;
    const int Tw = 2 * qblk + qh;             // wave's diagonal 32-key tile
    const int R = (qblk + 2) >> 1;            // rounds (pairs of 64-key tiles)

    const unsigned short* qp = Qh + kvbase + (size_t)(q0 + ln) * DK + hi * 8;
    bf16x8 qbv[4];
    #pragma unroll
    for (int c = 0; c < 4; ++c) qbv[c] = *(const bf16x8*)(qp + c * 16);

    f32x16 oa0 = {0,0,0,0,0,0,0,0,0,0,0,0,0,0,0,0};
    f32x16 oa1 = {0,0,0,0,0,0,0,0,0,0,0,0,0,0,0,0};
    float m = -1e30f, ls = 0.f;

    auto stage = [&](int bufb, int r){
      const int k0A = (2 * r) * 64;
      const int k0B = k0A + 64;
      const bool haveB = (2 * r + 1) <= qblk;
      #pragma unroll
      for (int i = 0; i < 2; ++i){
        const int c = i * 256 + tid;
        const int row = c >> 3;
        const int slot = (c & 7) ^ (row & 7);
        const int ldso = (i * 256 + wid * 64) * 8;   // shorts, wave-uniform
        gload_lds16(Kh  + kvbase + (size_t)(k0A + row) * DK + slot * 8, &SL[bufb][0][ldso]);
        gload_lds16(VhT + kvbase + (size_t)row * SS + k0A + slot * 8,   &SL[bufb][1][ldso]);
        if (haveB){
          gload_lds16(Kh  + kvbase + (size_t)(k0B + row) * DK + slot * 8, &SL[bufb][2][ldso]);
          gload_lds16(VhT + kvbase + (size_t)row * SS + k0B + slot * 8,   &SL[bufb][3][ldso]);
        }
      }
    };

    stage(0, 0);
    int cur = 0;
    #pragma unroll 1
    for (int r = 0; r < R; ++r){
      __syncthreads();                        // buf[cur] staged (vmcnt drained)
      if (r + 1 < R) stage(cur ^ 1, r + 1);   // next round's loads fly under compute

      const int t = 2 * r + pp;
      if (t <= qblk){
        const unsigned short* Kb = SL[cur][pp * 2];
        const unsigned short* Vb = SL[cur][pp * 2 + 1];

        // S^T (log2 domain) for key sub-tiles a/b of this 64-key tile
        f32x16 sta = {0,0,0,0,0,0,0,0,0,0,0,0,0,0,0,0};
        f32x16 stb = {0,0,0,0,0,0,0,0,0,0,0,0,0,0,0,0};
        __builtin_amdgcn_s_setprio(1);
        #pragma unroll
        for (int c = 0; c < 4; ++c){
          const int po = ((c * 2 + hi) ^ (ln & 7)) * 8;
          bf16x8 kfa = *(const bf16x8*)&Kb[ln * 64 + po];
          bf16x8 kfb = *(const bf16x8*)&Kb[(32 + ln) * 64 + po];
          sta = __builtin_amdgcn_mfma_f32_32x32x16_bf16(kfa, qbv[c], sta, 0, 0, 0);
          stb = __builtin_amdgcn_mfma_f32_32x32x16_bf16(kfb, qbv[c], stb, 0, 0, 0);
        }
        __builtin_amdgcn_s_setprio(0);

        // causal mask: 32-key tiles ta=2t, tb=2t+1 vs wave diag Tw
        const int ta = 2 * t, tb = 2 * t + 1;
        if (tb == Tw){
          #pragma unroll
          for (int rr = 0; rr < 16; ++rr){
            int kg = (rr & 3) + 8 * (rr >> 2) + 4 * hi;
            if (kg > ln) stb[rr] = -1e30f;
          }
        } else if (ta == Tw){
          #pragma unroll
          for (int rr = 0; rr < 16; ++rr){
            int kg = (rr & 3) + 8 * (rr >> 2) + 4 * hi;
            if (kg > ln) sta[rr] = -1e30f;
            stb[rr] = -1e30f;
          }
        }

        // tree max
        float tm[8];
        #pragma unroll
        for (int i = 0; i < 8; ++i)
          tm[i] = fmaxf(fmaxf(sta[2*i], sta[2*i+1]), fmaxf(stb[2*i], stb[2*i+1]));
        float mx = fmaxf(fmaxf(fmaxf(tm[0], tm[1]), fmaxf(tm[2], tm[3])),
                         fmaxf(fmaxf(tm[4], tm[5]), fmaxf(tm[6], tm[7])));
        mx = fmaxf(mx, __shfl_xor(mx, 32));

        // defer-max rescale
        if (__any(mx > m + DEFER_THR)){
          const float mn = fmaxf(m, mx);
          const float fac = __builtin_amdgcn_exp2f(m - mn);
          m = mn;
          ls *= fac;
          #pragma unroll
          for (int rr = 0; rr < 16; ++rr){ oa0[rr] *= fac; oa1[rr] *= fac; }
        }

        // P = exp2(st - m), tree sum
        #pragma unroll
        for (int rr = 0; rr < 16; ++rr){
          sta[rr] = __builtin_amdgcn_exp2f(sta[rr] - m);
          stb[rr] = __builtin_amdgcn_exp2f(stb[rr] - m);
        }
        float sm[8];
        #pragma unroll
        for (int i = 0; i < 8; ++i)
          sm[i] = (sta[2*i] + sta[2*i+1]) + (stb[2*i] + stb[2*i+1]);
        float rsum = ((sm[0] + sm[1]) + (sm[2] + sm[3])) + ((sm[4] + sm[5]) + (sm[6] + sm[7]));
        rsum += __shfl_xor(rsum, 32);
        ls += rsum;

        // P^T -> bf16 B-fragments
        u32 ca[8], cb[8];
        #pragma unroll
        for (int i = 0; i < 8; ++i){
          asm("v_cvt_pk_bf16_f32 %0, %1, %2" : "=v"(ca[i]) : "v"(sta[2*i]), "v"(sta[2*i+1]));
          asm("v_cvt_pk_bf16_f32 %0, %1, %2" : "=v"(cb[i]) : "v"(stb[2*i]), "v"(stb[2*i+1]));
        }
        u32 w0[4], w1[4], w2[4], w3[4];
        swap_half(ca[0], ca[2], hi, w0[0], w0[2]);
        swap_half(ca[1], ca[3], hi, w0[1], w0[3]);
        swap_half(ca[4], ca[6], hi, w1[0], w1[2]);
        swap_half(ca[5], ca[7], hi, w1[1], w1[3]);
        swap_half(cb[0], cb[2], hi, w2[0], w2[2]);
        swap_half(cb[1], cb[3], hi, w2[1], w2[3]);
        swap_half(cb[4], cb[6], hi, w3[0], w3[2]);
        swap_half(cb[5], cb[7], hi, w3[1], w3[3]);
        bf16x8 pf[4];
        __builtin_memcpy(&pf[0], w0, 16);
        __builtin_memcpy(&pf[1], w1, 16);
        __builtin_memcpy(&pf[2], w2, 16);
        __builtin_memcpy(&pf[3], w3, 16);

        // O^T += V^T * P^T
        __builtin_amdgcn_s_setprio(1);
        #pragma unroll
        for (int ks = 0; ks < 4; ++ks){
          const int po = ((ks * 2 + hi) ^ (ln & 7)) * 8;
          bf16x8 v0 = *(const bf16x8*)&Vb[ln * 64 + po];
          bf16x8 v1 = *(const bf16x8*)&Vb[(32 + ln) * 64 + po];
          oa0 = __builtin_amdgcn_mfma_f32_32x32x16_bf16(v0, pf[ks], oa0, 0, 0, 0);
          oa1 = __builtin_amdgcn_mfma_f32_32x32x16_bf16(v1, pf[ks], oa1, 0, 0, 0);
        }
        __builtin_amdgcn_s_setprio(0);
      }
      cur ^= 1;
    }
    __syncthreads();                          // last round's reads done before SL reuse

    // ---- 2-way split-K combine (exp2 domain), uses buffer set 0 ----
    float* oL  = (float*)&SL[0][0][0];        // [2][32][64] f32 = 16 KB
    float* mLs = (float*)&SL[0][2][0];        // mL[2][32] | lsL[2][32]
    if (wid >= 2){
      const int w = wid - 2;
      #pragma unroll
      for (int rr = 0; rr < 16; ++rr){
        oL[(w * 32 + rr) * 64 + lane]      = oa0[rr];
        oL[(w * 32 + 16 + rr) * 64 + lane] = oa1[rr];
      }
      if (hi == 0){ mLs[w * 32 + ln] = m; mLs[64 + w * 32 + ln] = ls; }
    }
    __syncthreads();
    if (wid < 2){
      const float m1  = mLs[wid * 32 + ln];
      const float ls1 = mLs[64 + wid * 32 + ln];
      const float mstar = fmaxf(m, m1);
      const float f0 = __builtin_amdgcn_exp2f(m  - mstar);
      const float f1 = __builtin_amdgcn_exp2f(m1 - mstar);
      const float inv = 1.0f / (f0 * ls + f1 * ls1);
      const size_t rowbase = ((size_t)b * SS + q0 + ln) * D_MODEL + h * DK;
      #pragma unroll
      for (int g = 0; g < 4; ++g){
        ushort4 o4;
        o4.x = f2bf((f0 * oa0[4*g + 0] + f1 * oL[(wid * 32 + 4*g + 0) * 64 + lane]) * inv);
        o4.y = f2bf((f0 * oa0[4*g + 1] + f1 * oL[(wid * 32 + 4*g + 1) * 64 + lane]) * inv);
        o4.z = f2bf((f0 * oa0[4*g + 2] + f1 * oL[(wid * 32 + 4*g + 2) * 64 + lane]) * inv);
        o4.w = f2bf((f0 * oa0[4*g + 3] + f1 * oL[(wid * 32 + 4*g + 3) * 64 + lane]) * inv);
        *(ushort4*)&Oc[rowbase + 8*g + 4*hi] = o4;
      }
      #pragma unroll
      for (int g = 0; g < 4; ++g){
        ushort4 o4;
        o4.x = f2bf((f0 * oa1[4*g + 0] + f1 * oL[(wid * 32 + 16 + 4*g + 0) * 64 + lane]) * inv);
        o4.y = f2bf((f0 * oa1[4*g + 1] + f1 * oL[(wid * 32 + 16 + 4*g + 1) * 64 + lane]) * inv);
        o4.z = f2bf((f0 * oa1[4*g + 2] + f1 * oL[(wid * 32 + 16 + 4*g + 2) * 64 + lane]) * inv);
        o4.w = f2bf((f0 * oa1[4*g + 3] + f1 * oL[(wid * 32 + 16 + 4*g + 3) * 64 + lane]) * inv);
        *(ushort4*)&Oc[rowbase + 32 + 8*g + 4*hi] = o4;
      }
    }
    __syncthreads();                          // combine reads done before next segment stages
  }
}

extern "C" void kernel_launch(void* const* d_in, const int* in_sizes, int n_in,
                              void* d_out, int out_size, void* d_ws, size_t ws_size,
                              hipStream_t stream){
  const float* q  = (const float*)d_in[0];
  const float* k  = (const float*)d_in[1];
  const float* v  = (const float*)d_in[2];
  // d_in[3]: causal mask (deterministic tril) — hardcoded in attn kernel
  const float* wq = (const float*)d_in[4];
  const float* wk = (const float*)d_in[5];
  const float* wv = (const float*)d_in[6];
  const float* wo = (const float*)d_in[7];
  float* out = (float*)d_out;

  char* ws = (char*)d_ws;
  const size_t MB = 1024 * 1024;
  unsigned short* WqkvT  = (unsigned short*)(ws + 0 * MB);    // 6 MB
  unsigned short* woT    = (unsigned short*)(ws + 6 * MB);    // 2 MB
  unsigned short* Qh     = (unsigned short*)(ws + 8 * MB);
  unsigned short* Kh     = (unsigned short*)(ws + 16 * MB);
  unsigned short* VhT    = (unsigned short*)(ws + 24 * MB);
  unsigned short* attnb  = (unsigned short*)(ws + 32 * MB);

  dim3 tg(16, 16, 4);
  transpose_cvt4<<<tg, 256, 0, stream>>>(wq, wk, wv, wo, WqkvT, woT);

  dim3 gqkv(M_TOT / 128, 3 * D_MODEL / 128);   // (32, 24) = 768 blocks
  gemm_qkv<<<gqkv, 256, 0, stream>>>(q, k, v, WqkvT, Qh, Kh, VhT);

  dim3 ga(BB * NH, SS / 128);                  // (32 bh, 16 px): folded pairs
  attn_kernel<<<ga, 256, 0, stream>>>(Qh, Kh, VhT, attnb);

  dim3 go(M_TOT / 64, D_MODEL / 128);          // (64, 8) = 512 blocks
  gemm_o64<<<go, 256, 0, stream>>>(attnb, woT, out);
}

// Round 18
// 114.471 us; speedup vs baseline: 1.1996x; 1.0373x over previous
//
#include <hip/hip_runtime.h>

#define D_MODEL 1024
#define NH 16
#define DK 64
#define BB 2
#define SS 2048
#define M_TOT (BB*SS)

typedef float f32x4 __attribute__((ext_vector_type(4)));
typedef float f32x16 __attribute__((ext_vector_type(16)));
typedef __bf16 bf16x8 __attribute__((ext_vector_type(8)));
typedef unsigned int u32;

// 0.125 (1/sqrt(dk)) * log2(e): folds softmax scaling + base-2 exp into Q
#define QSCALE 0.1803368801f
#define DEFER_THR 11.5416f   // 8 * log2(e)

__device__ __forceinline__ unsigned short f2bf(float f){
  unsigned int u = __float_as_uint(f);
  unsigned int r = (u + 0x7fffu + ((u >> 16) & 1u)) >> 16;
  return (unsigned short)r;
}

__device__ __forceinline__ void gload_lds16(const void* g, void* l){
  __builtin_amdgcn_global_load_lds((const __attribute__((address_space(1))) void*)g,
                                   (__attribute__((address_space(3))) void*)l,
                                   16, 0, 0);
}

// exchange 32-lane halves: x = {lo: a.lo, hi: b.lo}, y = {lo: a.hi, hi: b.hi}
__device__ __forceinline__ void swap_half(u32 a, u32 b, int hi, u32& x, u32& y){
#if __has_builtin(__builtin_amdgcn_permlane32_swap)
  typedef unsigned int uint2v __attribute__((ext_vector_type(2)));
  uint2v r = __builtin_amdgcn_permlane32_swap(a, b, false, false);
  x = r.x; y = r.y;
#else
  u32 as = __shfl_xor(a, 32);
  u32 bs = __shfl_xor(b, 32);
  x = hi ? bs : a;
  y = hi ? b  : as;
#endif
}

// ------------- fp32 [K][N] -> bf16 [N][K] transpose-convert, 4 mats -------------
__global__ __launch_bounds__(256) void transpose_cvt4(const float* __restrict__ wq,
                                                      const float* __restrict__ wk,
                                                      const float* __restrict__ wv,
                                                      const float* __restrict__ wo,
                                                      unsigned short* __restrict__ WqkvT,
                                                      unsigned short* __restrict__ woT){
  __shared__ float tile[64][65];
  const int which = blockIdx.z;
  const float* w = (which == 0) ? wq : (which == 1) ? wk : (which == 2) ? wv : wo;
  unsigned short* wt = (which == 3) ? woT : (WqkvT + (size_t)which * 1024 * 1024);
  const int N = D_MODEL;
  const int bx = blockIdx.x * 64;
  const int by = blockIdx.y * 64;
  const int t = threadIdx.x;
  #pragma unroll
  for (int i = 0; i < 16; ++i){
    int idx = t + i * 256;
    int r = idx >> 6, c = idx & 63;
    tile[r][c] = w[(size_t)(by + r) * N + bx + c];
  }
  __syncthreads();
  #pragma unroll
  for (int i = 0; i < 16; ++i){
    int idx = t + i * 256;
    int r = idx >> 6, c = idx & 63;
    wt[(size_t)(bx + r) * N + by + c] = f2bf(tile[c][r]);
  }
}

// ---------------- fused QKV projection GEMM, fp32 A, reg-staged convert ----------------
// A (fp32) is loaded to registers (coalesced float4), converted to bf16 via
// v_cvt_pk_bf16_f32, and ds_write'n into the r12-proven LINEAR bf16 layout
// (32 KB LDS total). T14 split: loads issued right after the barrier, MFMA
// compute hides the latency, cvt+write lands in buf^1 before the next barrier.
// seg 0 -> Qh scatter (pre-scaled by QSCALE), seg 1 -> Kh, seg 2 -> VhT.
__global__ __launch_bounds__(256) void gemm_qkv(const float* __restrict__ Aq,
                                                const float* __restrict__ Ak,
                                                const float* __restrict__ Av,
                                                const unsigned short* __restrict__ WT,
                                                unsigned short* __restrict__ Qh,
                                                unsigned short* __restrict__ Kh,
                                                unsigned short* __restrict__ VhT){
  __shared__ unsigned short Al[2][128 * 32];   // 16 KB, linear r12 layout
  __shared__ unsigned short Bl[2][128 * 32];   // 16 KB, linear r12 layout
  const int tid = threadIdx.x;
  const int wid = tid >> 6, lane = tid & 63;
  const int lr = lane & 15, lg = lane >> 4;
  const int wm = wid >> 1, wn = wid & 1;
  const int bm = blockIdx.x, bn = blockIdx.y;
  const int seg = bn >> 3;
  const float* A = (seg == 0) ? Aq : (seg == 1) ? Ak : Av;
  const int K = D_MODEL;

  f32x4 acc[4][4];
  #pragma unroll
  for (int i = 0; i < 4; ++i)
    #pragma unroll
    for (int j = 0; j < 4; ++j)
      acc[i][j] = (f32x4){0.f, 0.f, 0.f, 0.f};

  const int arow  = tid >> 3;     // 0..31 (pass p adds p*32)
  const int aslot = tid & 7;      // float4 slot within the 32-col row

  f32x4 ar[4];                    // staged fp32 A (16 VGPRs)

  auto loadA = [&](int kt){
    #pragma unroll
    for (int p = 0; p < 4; ++p)
      ar[p] = *(const f32x4*)&A[(size_t)(bm * 128 + p * 32 + arow) * K + kt * 32 + aslot * 4];
  };
  auto writeA = [&](int buf){
    #pragma unroll
    for (int p = 0; p < 4; ++p){
      u32 c0, c1;
      asm("v_cvt_pk_bf16_f32 %0, %1, %2" : "=v"(c0) : "v"(ar[p][0]), "v"(ar[p][1]));
      asm("v_cvt_pk_bf16_f32 %0, %1, %2" : "=v"(c1) : "v"(ar[p][2]), "v"(ar[p][3]));
      uint2 wv2 = {c0, c1};
      *(uint2*)&Al[buf][(p * 32 + arow) * 32 + aslot * 4] = wv2;
    }
  };
  auto stageB = [&](int buf, int kt){
    #pragma unroll
    for (int rr = 0; rr < 2; ++rr){
      int vt = tid + rr * 256;
      int row = vt >> 2, c8 = (vt & 3) * 8;
      gload_lds16(WT + (size_t)(bn * 128 + row) * K + kt * 32 + c8,
                  &Bl[buf][(wid << 9) + rr * 2048]);
    }
  };

  // prologue: fill buffer 0
  loadA(0);
  stageB(0, 0);
  writeA(0);

  int cur = 0;
  for (int kt = 0; kt < 32; ++kt){
    __syncthreads();               // buf[cur] ready (B vmcnt drained, A writes visible)
    if (kt + 1 < 32){
      loadA(kt + 1);               // A loads oldest in VMEM queue
      stageB(cur ^ 1, kt + 1);     // B DMA behind them
    }
    bf16x8 af[4], bfr[4];
    #pragma unroll
    for (int i = 0; i < 4; ++i)
      af[i] = *(const bf16x8*)&Al[cur][(wm * 64 + i * 16 + lr) * 32 + lg * 8];
    #pragma unroll
    for (int j = 0; j < 4; ++j)
      bfr[j] = *(const bf16x8*)&Bl[cur][(wn * 64 + j * 16 + lr) * 32 + lg * 8];
    #pragma unroll
    for (int i = 0; i < 4; ++i)
      #pragma unroll
      for (int j = 0; j < 4; ++j)
        acc[i][j] = __builtin_amdgcn_mfma_f32_16x16x32_bf16(af[i], bfr[j], acc[i][j], 0, 0, 0);
    if (kt + 1 < 32) writeA(cur ^ 1);   // vmcnt wait lands AFTER the MFMA block
    cur ^= 1;
  }

  if (seg < 2){
    unsigned short* O = (seg == 0) ? Qh : Kh;
    const float sc = (seg == 0) ? QSCALE : 1.0f;
    #pragma unroll
    for (int i = 0; i < 4; ++i){
      int row0 = bm * 128 + wm * 64 + i * 16 + lg * 4;
      #pragma unroll
      for (int j = 0; j < 4; ++j){
        int colseg = (bn & 7) * 128 + wn * 64 + j * 16 + lr;
        int h = colseg >> 6, dk = colseg & 63;
        #pragma unroll
        for (int p = 0; p < 4; ++p){
          int rowm = row0 + p;
          int b = rowm >> 11, s = rowm & 2047;
          O[((size_t)(b * NH + h) * SS + s) * DK + dk] = f2bf(acc[i][j][p] * sc);
        }
      }
    }
  } else {
    #pragma unroll
    for (int i = 0; i < 4; ++i){
      int row0 = bm * 128 + wm * 64 + i * 16 + lg * 4;
      int b = row0 >> 11, s = row0 & 2047;
      #pragma unroll
      for (int j = 0; j < 4; ++j){
        int colseg = (bn & 7) * 128 + wn * 64 + j * 16 + lr;
        int h = colseg >> 6, dk = colseg & 63;
        ushort4 o4;
        o4.x = f2bf(acc[i][j][0]); o4.y = f2bf(acc[i][j][1]);
        o4.z = f2bf(acc[i][j][2]); o4.w = f2bf(acc[i][j][3]);
        *(ushort4*)&VhT[((size_t)(b * NH + h) * DK + dk) * SS + s] = o4;
      }
    }
  }
}

// ---------------- output projection GEMM (BM=64 for occupancy) ----------------
__global__ __launch_bounds__(256) void gemm_o64(const unsigned short* __restrict__ A,
                                                const unsigned short* __restrict__ Bt,
                                                float* __restrict__ O){
  __shared__ unsigned short Al[2][64 * 32];
  __shared__ unsigned short Bl[2][128 * 32];
  const int tid = threadIdx.x;
  const int wid = tid >> 6, lane = tid & 63;
  const int lr = lane & 15, lg = lane >> 4;
  const int wm = wid >> 1, wn = wid & 1;
  const int bm = blockIdx.x, bn = blockIdx.y;
  const int K = D_MODEL;

  f32x4 acc[2][4];
  #pragma unroll
  for (int i = 0; i < 2; ++i)
    #pragma unroll
    for (int j = 0; j < 4; ++j)
      acc[i][j] = (f32x4){0.f, 0.f, 0.f, 0.f};

  auto stage = [&](int buf, int kt){
    {
      int row = tid >> 2, c8 = (tid & 3) * 8;
      gload_lds16(A + (size_t)(bm * 64 + row) * K + kt * 32 + c8,
                  &Al[buf][wid << 9]);
    }
    #pragma unroll
    for (int r = 0; r < 2; ++r){
      int vt = tid + r * 256;
      int row = vt >> 2, c8 = (vt & 3) * 8;
      gload_lds16(Bt + (size_t)(bn * 128 + row) * K + kt * 32 + c8,
                  &Bl[buf][(wid << 9) + r * 2048]);
    }
  };

  stage(0, 0);
  int cur = 0;
  for (int kt = 0; kt < 32; ++kt){
    __syncthreads();
    if (kt + 1 < 32) stage(cur ^ 1, kt + 1);
    bf16x8 af[2], bfr[4];
    #pragma unroll
    for (int i = 0; i < 2; ++i)
      af[i] = *(const bf16x8*)&Al[cur][(wm * 32 + i * 16 + lr) * 32 + lg * 8];
    #pragma unroll
    for (int j = 0; j < 4; ++j)
      bfr[j] = *(const bf16x8*)&Bl[cur][(wn * 64 + j * 16 + lr) * 32 + lg * 8];
    #pragma unroll
    for (int i = 0; i < 2; ++i)
      #pragma unroll
      for (int j = 0; j < 4; ++j)
        acc[i][j] = __builtin_amdgcn_mfma_f32_16x16x32_bf16(af[i], bfr[j], acc[i][j], 0, 0, 0);
    cur ^= 1;
  }

  #pragma unroll
  for (int i = 0; i < 2; ++i){
    int row0 = bm * 64 + wm * 32 + i * 16 + lg * 4;
    #pragma unroll
    for (int j = 0; j < 4; ++j){
      int col = bn * 128 + wn * 64 + j * 16 + lr;
      #pragma unroll
      for (int p = 0; p < 4; ++p)
        O[(size_t)(row0 + p) * D_MODEL + col] = acc[i][j][p];
    }
  }
}

// ---------------- causal flash attention: 4-wave split-K + fold + LDS dbuf ----------------
// (round-12 proven kernel, 51.0 us) Grid (bh=32, px=16). Block processes
// qblk = px then 31-px (~17.5 rounds flat). m97 stage-ahead order:
// __syncthreads(); stage(next -> buf^1); compute(buf). 64 KB LDS dbuf.
__global__ __launch_bounds__(256) void attn_kernel(const unsigned short* __restrict__ Qh,
                                                   const unsigned short* __restrict__ Kh,
                                                   const unsigned short* __restrict__ VhT,
                                                   unsigned short* __restrict__ Oc){
  __shared__ unsigned short SL[2][4][4096];   // [buf][KA|VA|KB|VB][8KB], 64 KB
  const int bh = blockIdx.x;                  // bh%8 -> XCD stickiness
  const int px = blockIdx.y;                  // 0..15
  const int tid = threadIdx.x, wid = tid >> 6, lane = tid & 63;
  const int ln = lane & 31, hi = lane >> 5;
  const int qh = wid & 1, pp = wid >> 1;      // q-half, K-parity
  const int b = bh >> 4, h = bh & 15;
  const size_t kvbase = (size_t)bh * SS * DK;

  #pragma unroll 1
  for (int segq = 0; segq < 2; ++segq){
    const int qblk = segq ? (31 - px) : px;
    const int q0 = qblk * 64 + qh * 32;
    const int Tw = 2 * qblk + qh;             // wave's diagonal 32-key tile
    const int R = (qblk + 2) >> 1;            // rounds (pairs of 64-key tiles)

    const unsigned short* qp = Qh + kvbase + (size_t)(q0 + ln) * DK + hi * 8;
    bf16x8 qbv[4];
    #pragma unroll
    for (int c = 0; c < 4; ++c) qbv[c] = *(const bf16x8*)(qp + c * 16);

    f32x16 oa0 = {0,0,0,0,0,0,0,0,0,0,0,0,0,0,0,0};
    f32x16 oa1 = {0,0,0,0,0,0,0,0,0,0,0,0,0,0,0,0};
    float m = -1e30f, ls = 0.f;

    auto stage = [&](int bufb, int r){
      const int k0A = (2 * r) * 64;
      const int k0B = k0A + 64;
      const bool haveB = (2 * r + 1) <= qblk;
      #pragma unroll
      for (int i = 0; i < 2; ++i){
        const int c = i * 256 + tid;
        const int row = c >> 3;
        const int slot = (c & 7) ^ (row & 7);
        const int ldso = (i * 256 + wid * 64) * 8;   // shorts, wave-uniform
        gload_lds16(Kh  + kvbase + (size_t)(k0A + row) * DK + slot * 8, &SL[bufb][0][ldso]);
        gload_lds16(VhT + kvbase + (size_t)row * SS + k0A + slot * 8,   &SL[bufb][1][ldso]);
        if (haveB){
          gload_lds16(Kh  + kvbase + (size_t)(k0B + row) * DK + slot * 8, &SL[bufb][2][ldso]);
          gload_lds16(VhT + kvbase + (size_t)row * SS + k0B + slot * 8,   &SL[bufb][3][ldso]);
        }
      }
    };

    stage(0, 0);
    int cur = 0;
    #pragma unroll 1
    for (int r = 0; r < R; ++r){
      __syncthreads();                        // buf[cur] staged (vmcnt drained)
      if (r + 1 < R) stage(cur ^ 1, r + 1);   // next round's loads fly under compute

      const int t = 2 * r + pp;
      if (t <= qblk){
        const unsigned short* Kb = SL[cur][pp * 2];
        const unsigned short* Vb = SL[cur][pp * 2 + 1];

        // S^T (log2 domain) for key sub-tiles a/b of this 64-key tile
        f32x16 sta = {0,0,0,0,0,0,0,0,0,0,0,0,0,0,0,0};
        f32x16 stb = {0,0,0,0,0,0,0,0,0,0,0,0,0,0,0,0};
        __builtin_amdgcn_s_setprio(1);
        #pragma unroll
        for (int c = 0; c < 4; ++c){
          const int po = ((c * 2 + hi) ^ (ln & 7)) * 8;
          bf16x8 kfa = *(const bf16x8*)&Kb[ln * 64 + po];
          bf16x8 kfb = *(const bf16x8*)&Kb[(32 + ln) * 64 + po];
          sta = __builtin_amdgcn_mfma_f32_32x32x16_bf16(kfa, qbv[c], sta, 0, 0, 0);
          stb = __builtin_amdgcn_mfma_f32_32x32x16_bf16(kfb, qbv[c], stb, 0, 0, 0);
        }
        __builtin_amdgcn_s_setprio(0);

        // causal mask: 32-key tiles ta=2t, tb=2t+1 vs wave diag Tw
        const int ta = 2 * t, tb = 2 * t + 1;
        if (tb == Tw){
          #pragma unroll
          for (int rr = 0; rr < 16; ++rr){
            int kg = (rr & 3) + 8 * (rr >> 2) + 4 * hi;
            if (kg > ln) stb[rr] = -1e30f;
          }
        } else if (ta == Tw){
          #pragma unroll
          for (int rr = 0; rr < 16; ++rr){
            int kg = (rr & 3) + 8 * (rr >> 2) + 4 * hi;
            if (kg > ln) sta[rr] = -1e30f;
            stb[rr] = -1e30f;
          }
        }

        // tree max
        float tm[8];
        #pragma unroll
        for (int i = 0; i < 8; ++i)
          tm[i] = fmaxf(fmaxf(sta[2*i], sta[2*i+1]), fmaxf(stb[2*i], stb[2*i+1]));
        float mx = fmaxf(fmaxf(fmaxf(tm[0], tm[1]), fmaxf(tm[2], tm[3])),
                         fmaxf(fmaxf(tm[4], tm[5]), fmaxf(tm[6], tm[7])));
        mx = fmaxf(mx, __shfl_xor(mx, 32));

        // defer-max rescale
        if (__any(mx > m + DEFER_THR)){
          const float mn = fmaxf(m, mx);
          const float fac = __builtin_amdgcn_exp2f(m - mn);
          m = mn;
          ls *= fac;
          #pragma unroll
          for (int rr = 0; rr < 16; ++rr){ oa0[rr] *= fac; oa1[rr] *= fac; }
        }

        // P = exp2(st - m), tree sum
        #pragma unroll
        for (int rr = 0; rr < 16; ++rr){
          sta[rr] = __builtin_amdgcn_exp2f(sta[rr] - m);
          stb[rr] = __builtin_amdgcn_exp2f(stb[rr] - m);
        }
        float sm[8];
        #pragma unroll
        for (int i = 0; i < 8; ++i)
          sm[i] = (sta[2*i] + sta[2*i+1]) + (stb[2*i] + stb[2*i+1]);
        float rsum = ((sm[0] + sm[1]) + (sm[2] + sm[3])) + ((sm[4] + sm[5]) + (sm[6] + sm[7]));
        rsum += __shfl_xor(rsum, 32);
        ls += rsum;

        // P^T -> bf16 B-fragments
        u32 ca[8], cb[8];
        #pragma unroll
        for (int i = 0; i < 8; ++i){
          asm("v_cvt_pk_bf16_f32 %0, %1, %2" : "=v"(ca[i]) : "v"(sta[2*i]), "v"(sta[2*i+1]));
          asm("v_cvt_pk_bf16_f32 %0, %1, %2" : "=v"(cb[i]) : "v"(stb[2*i]), "v"(stb[2*i+1]));
        }
        u32 w0[4], w1[4], w2[4], w3[4];
        swap_half(ca[0], ca[2], hi, w0[0], w0[2]);
        swap_half(ca[1], ca[3], hi, w0[1], w0[3]);
        swap_half(ca[4], ca[6], hi, w1[0], w1[2]);
        swap_half(ca[5], ca[7], hi, w1[1], w1[3]);
        swap_half(cb[0], cb[2], hi, w2[0], w2[2]);
        swap_half(cb[1], cb[3], hi, w2[1], w2[3]);
        swap_half(cb[4], cb[6], hi, w3[0], w3[2]);
        swap_half(cb[5], cb[7], hi, w3[1], w3[3]);
        bf16x8 pf[4];
        __builtin_memcpy(&pf[0], w0, 16);
        __builtin_memcpy(&pf[1], w1, 16);
        __builtin_memcpy(&pf[2], w2, 16);
        __builtin_memcpy(&pf[3], w3, 16);

        // O^T += V^T * P^T
        __builtin_amdgcn_s_setprio(1);
        #pragma unroll
        for (int ks = 0; ks < 4; ++ks){
          const int po = ((ks * 2 + hi) ^ (ln & 7)) * 8;
          bf16x8 v0 = *(const bf16x8*)&Vb[ln * 64 + po];
          bf16x8 v1 = *(const bf16x8*)&Vb[(32 + ln) * 64 + po];
          oa0 = __builtin_amdgcn_mfma_f32_32x32x16_bf16(v0, pf[ks], oa0, 0, 0, 0);
          oa1 = __builtin_amdgcn_mfma_f32_32x32x16_bf16(v1, pf[ks], oa1, 0, 0, 0);
        }
        __builtin_amdgcn_s_setprio(0);
      }
      cur ^= 1;
    }
    __syncthreads();                          // last round's reads done before SL reuse

    // ---- 2-way split-K combine (exp2 domain), uses buffer set 0 ----
    float* oL  = (float*)&SL[0][0][0];        // [2][32][64] f32 = 16 KB
    float* mLs = (float*)&SL[0][2][0];        // mL[2][32] | lsL[2][32]
    if (wid >= 2){
      const int w = wid - 2;
      #pragma unroll
      for (int rr = 0; rr < 16; ++rr){
        oL[(w * 32 + rr) * 64 + lane]      = oa0[rr];
        oL[(w * 32 + 16 + rr) * 64 + lane] = oa1[rr];
      }
      if (hi == 0){ mLs[w * 32 + ln] = m; mLs[64 + w * 32 + ln] = ls; }
    }
    __syncthreads();
    if (wid < 2){
      const float m1  = mLs[wid * 32 + ln];
      const float ls1 = mLs[64 + wid * 32 + ln];
      const float mstar = fmaxf(m, m1);
      const float f0 = __builtin_amdgcn_exp2f(m  - mstar);
      const float f1 = __builtin_amdgcn_exp2f(m1 - mstar);
      const float inv = 1.0f / (f0 * ls + f1 * ls1);
      const size_t rowbase = ((size_t)b * SS + q0 + ln) * D_MODEL + h * DK;
      #pragma unroll
      for (int g = 0; g < 4; ++g){
        ushort4 o4;
        o4.x = f2bf((f0 * oa0[4*g + 0] + f1 * oL[(wid * 32 + 4*g + 0) * 64 + lane]) * inv);
        o4.y = f2bf((f0 * oa0[4*g + 1] + f1 * oL[(wid * 32 + 4*g + 1) * 64 + lane]) * inv);
        o4.z = f2bf((f0 * oa0[4*g + 2] + f1 * oL[(wid * 32 + 4*g + 2) * 64 + lane]) * inv);
        o4.w = f2bf((f0 * oa0[4*g + 3] + f1 * oL[(wid * 32 + 4*g + 3) * 64 + lane]) * inv);
        *(ushort4*)&Oc[rowbase + 8*g + 4*hi] = o4;
      }
      #pragma unroll
      for (int g = 0; g < 4; ++g){
        ushort4 o4;
        o4.x = f2bf((f0 * oa1[4*g + 0] + f1 * oL[(wid * 32 + 16 + 4*g + 0) * 64 + lane]) * inv);
        o4.y = f2bf((f0 * oa1[4*g + 1] + f1 * oL[(wid * 32 + 16 + 4*g + 1) * 64 + lane]) * inv);
        o4.z = f2bf((f0 * oa1[4*g + 2] + f1 * oL[(wid * 32 + 16 + 4*g + 2) * 64 + lane]) * inv);
        o4.w = f2bf((f0 * oa1[4*g + 3] + f1 * oL[(wid * 32 + 16 + 4*g + 3) * 64 + lane]) * inv);
        *(ushort4*)&Oc[rowbase + 32 + 8*g + 4*hi] = o4;
      }
    }
    __syncthreads();                          // combine reads done before next segment stages
  }
}

extern "C" void kernel_launch(void* const* d_in, const int* in_sizes, int n_in,
                              void* d_out, int out_size, void* d_ws, size_t ws_size,
                              hipStream_t stream){
  const float* q  = (const float*)d_in[0];
  const float* k  = (const float*)d_in[1];
  const float* v  = (const float*)d_in[2];
  // d_in[3]: causal mask (deterministic tril) — hardcoded in attn kernel
  const float* wq = (const float*)d_in[4];
  const float* wk = (const float*)d_in[5];
  const float* wv = (const float*)d_in[6];
  const float* wo = (const float*)d_in[7];
  float* out = (float*)d_out;

  char* ws = (char*)d_ws;
  const size_t MB = 1024 * 1024;
  unsigned short* WqkvT  = (unsigned short*)(ws + 0 * MB);    // 6 MB
  unsigned short* woT    = (unsigned short*)(ws + 6 * MB);    // 2 MB
  unsigned short* Qh     = (unsigned short*)(ws + 8 * MB);
  unsigned short* Kh     = (unsigned short*)(ws + 16 * MB);
  unsigned short* VhT    = (unsigned short*)(ws + 24 * MB);
  unsigned short* attnb  = (unsigned short*)(ws + 32 * MB);

  dim3 tg(16, 16, 4);
  transpose_cvt4<<<tg, 256, 0, stream>>>(wq, wk, wv, wo, WqkvT, woT);

  dim3 gqkv(M_TOT / 128, 3 * D_MODEL / 128);   // (32, 24) = 768 blocks
  gemm_qkv<<<gqkv, 256, 0, stream>>>(q, k, v, WqkvT, Qh, Kh, VhT);

  dim3 ga(BB * NH, SS / 128);                  // (32 bh, 16 px): folded pairs
  attn_kernel<<<ga, 256, 0, stream>>>(Qh, Kh, VhT, attnb);

  dim3 go(M_TOT / 64, D_MODEL / 128);          // (64, 8) = 512 blocks
  gemm_o64<<<go, 256, 0, stream>>>(attnb, woT, out);
}

// Round 19
// 114.172 us; speedup vs baseline: 1.2027x; 1.0026x over previous
//
#include <hip/hip_runtime.h>

#define D_MODEL 1024
#define NH 16
#define DK 64
#define BB 2
#define SS 2048
#define M_TOT (BB*SS)

typedef float f32x4 __attribute__((ext_vector_type(4)));
typedef float f32x16 __attribute__((ext_vector_type(16)));
typedef __bf16 bf16x8 __attribute__((ext_vector_type(8)));
typedef unsigned int u32;

// 0.125 (1/sqrt(dk)) * log2(e): folds softmax scaling + base-2 exp into Q
#define QSCALE 0.1803368801f
#define DEFER_THR 11.5416f   // 8 * log2(e)

__device__ __forceinline__ unsigned short f2bf(float f){
  unsigned int u = __float_as_uint(f);
  unsigned int r = (u + 0x7fffu + ((u >> 16) & 1u)) >> 16;
  return (unsigned short)r;
}

__device__ __forceinline__ void gload_lds16(const void* g, void* l){
  __builtin_amdgcn_global_load_lds((const __attribute__((address_space(1))) void*)g,
                                   (__attribute__((address_space(3))) void*)l,
                                   16, 0, 0);
}

// exchange 32-lane halves: x = {lo: a.lo, hi: b.lo}, y = {lo: a.hi, hi: b.hi}
__device__ __forceinline__ void swap_half(u32 a, u32 b, int hi, u32& x, u32& y){
#if __has_builtin(__builtin_amdgcn_permlane32_swap)
  typedef unsigned int uint2v __attribute__((ext_vector_type(2)));
  uint2v r = __builtin_amdgcn_permlane32_swap(a, b, false, false);
  x = r.x; y = r.y;
#else
  u32 as = __shfl_xor(a, 32);
  u32 bs = __shfl_xor(b, 32);
  x = hi ? bs : a;
  y = hi ? b  : as;
#endif
}

// ------------- fp32 [K][N] -> bf16 [N][K] transpose-convert, 4 mats -------------
__global__ __launch_bounds__(256) void transpose_cvt4(const float* __restrict__ wq,
                                                      const float* __restrict__ wk,
                                                      const float* __restrict__ wv,
                                                      const float* __restrict__ wo,
                                                      unsigned short* __restrict__ WqkvT,
                                                      unsigned short* __restrict__ woT){
  __shared__ float tile[64][65];
  const int which = blockIdx.z;
  const float* w = (which == 0) ? wq : (which == 1) ? wk : (which == 2) ? wv : wo;
  unsigned short* wt = (which == 3) ? woT : (WqkvT + (size_t)which * 1024 * 1024);
  const int N = D_MODEL;
  const int bx = blockIdx.x * 64;
  const int by = blockIdx.y * 64;
  const int t = threadIdx.x;
  #pragma unroll
  for (int i = 0; i < 16; ++i){
    int idx = t + i * 256;
    int r = idx >> 6, c = idx & 63;
    tile[r][c] = w[(size_t)(by + r) * N + bx + c];
  }
  __syncthreads();
  #pragma unroll
  for (int i = 0; i < 16; ++i){
    int idx = t + i * 256;
    int r = idx >> 6, c = idx & 63;
    wt[(size_t)(bx + r) * N + by + c] = f2bf(tile[c][r]);
  }
}

// ---------------- fused QKV projection GEMM, fp32 A, reg-staged convert ----------------
// A (fp32) loaded to regs (coalesced float4), converted via v_cvt_pk_bf16_f32,
// ds_write_b128 into the linear bf16 layout. Write pattern: arow=tid>>2 (64
// rows/pass, 2 passes), aslot=tid&3 -> each wave writes a contiguous 1 KB span
// = conflict-free b128 (r18 fix: b64 512B-span writes were 4-way).
// seg 0 -> Qh scatter (pre-scaled by QSCALE), seg 1 -> Kh, seg 2 -> VhT.
__global__ __launch_bounds__(256) void gemm_qkv(const float* __restrict__ Aq,
                                                const float* __restrict__ Ak,
                                                const float* __restrict__ Av,
                                                const unsigned short* __restrict__ WT,
                                                unsigned short* __restrict__ Qh,
                                                unsigned short* __restrict__ Kh,
                                                unsigned short* __restrict__ VhT){
  __shared__ unsigned short Al[2][128 * 32];   // 16 KB, linear layout
  __shared__ unsigned short Bl[2][128 * 32];   // 16 KB, linear layout
  const int tid = threadIdx.x;
  const int wid = tid >> 6, lane = tid & 63;
  const int lr = lane & 15, lg = lane >> 4;
  const int wm = wid >> 1, wn = wid & 1;
  const int bm = blockIdx.x, bn = blockIdx.y;
  const int seg = bn >> 3;
  const float* A = (seg == 0) ? Aq : (seg == 1) ? Ak : Av;
  const int K = D_MODEL;

  f32x4 acc[4][4];
  #pragma unroll
  for (int i = 0; i < 4; ++i)
    #pragma unroll
    for (int j = 0; j < 4; ++j)
      acc[i][j] = (f32x4){0.f, 0.f, 0.f, 0.f};

  const int arow  = tid >> 2;     // 0..63 (pass p adds p*64)
  const int aslot = tid & 3;      // 16B-bf16 slot (= 8 shorts = 8 floats)

  f32x4 ar[2][2];                 // [pass][half], 16 VGPRs

  auto loadA = [&](int kt){
    #pragma unroll
    for (int p = 0; p < 2; ++p){
      const float* base = &A[(size_t)(bm * 128 + p * 64 + arow) * K + kt * 32 + aslot * 8];
      ar[p][0] = *(const f32x4*)(base);
      ar[p][1] = *(const f32x4*)(base + 4);
    }
  };
  auto writeA = [&](int buf){
    #pragma unroll
    for (int p = 0; p < 2; ++p){
      u32 cc[4];
      asm("v_cvt_pk_bf16_f32 %0, %1, %2" : "=v"(cc[0]) : "v"(ar[p][0][0]), "v"(ar[p][0][1]));
      asm("v_cvt_pk_bf16_f32 %0, %1, %2" : "=v"(cc[1]) : "v"(ar[p][0][2]), "v"(ar[p][0][3]));
      asm("v_cvt_pk_bf16_f32 %0, %1, %2" : "=v"(cc[2]) : "v"(ar[p][1][0]), "v"(ar[p][1][1]));
      asm("v_cvt_pk_bf16_f32 %0, %1, %2" : "=v"(cc[3]) : "v"(ar[p][1][2]), "v"(ar[p][1][3]));
      uint4 wv4 = {cc[0], cc[1], cc[2], cc[3]};
      *(uint4*)&Al[buf][(p * 64 + arow) * 32 + aslot * 8] = wv4;   // b128, 1KB/wave span
    }
  };
  auto stageB = [&](int buf, int kt){
    #pragma unroll
    for (int rr = 0; rr < 2; ++rr){
      int vt = tid + rr * 256;
      int row = vt >> 2, c8 = (vt & 3) * 8;
      gload_lds16(WT + (size_t)(bn * 128 + row) * K + kt * 32 + c8,
                  &Bl[buf][(wid << 9) + rr * 2048]);
    }
  };

  // prologue: fill buffer 0
  loadA(0);
  stageB(0, 0);
  writeA(0);

  int cur = 0;
  for (int kt = 0; kt < 32; ++kt){
    __syncthreads();               // buf[cur] ready (B vmcnt drained, A writes visible)
    if (kt + 1 < 32){
      loadA(kt + 1);               // A loads oldest in VMEM queue
      stageB(cur ^ 1, kt + 1);     // B DMA behind them
    }
    bf16x8 af[4], bfr[4];
    #pragma unroll
    for (int i = 0; i < 4; ++i)
      af[i] = *(const bf16x8*)&Al[cur][(wm * 64 + i * 16 + lr) * 32 + lg * 8];
    #pragma unroll
    for (int j = 0; j < 4; ++j)
      bfr[j] = *(const bf16x8*)&Bl[cur][(wn * 64 + j * 16 + lr) * 32 + lg * 8];
    #pragma unroll
    for (int i = 0; i < 4; ++i)
      #pragma unroll
      for (int j = 0; j < 4; ++j)
        acc[i][j] = __builtin_amdgcn_mfma_f32_16x16x32_bf16(af[i], bfr[j], acc[i][j], 0, 0, 0);
    if (kt + 1 < 32) writeA(cur ^ 1);   // vmcnt wait lands AFTER the MFMA block
    cur ^= 1;
  }

  if (seg < 2){
    unsigned short* O = (seg == 0) ? Qh : Kh;
    const float sc = (seg == 0) ? QSCALE : 1.0f;
    #pragma unroll
    for (int i = 0; i < 4; ++i){
      int row0 = bm * 128 + wm * 64 + i * 16 + lg * 4;
      #pragma unroll
      for (int j = 0; j < 4; ++j){
        int colseg = (bn & 7) * 128 + wn * 64 + j * 16 + lr;
        int h = colseg >> 6, dk = colseg & 63;
        #pragma unroll
        for (int p = 0; p < 4; ++p){
          int rowm = row0 + p;
          int b = rowm >> 11, s = rowm & 2047;
          O[((size_t)(b * NH + h) * SS + s) * DK + dk] = f2bf(acc[i][j][p] * sc);
        }
      }
    }
  } else {
    #pragma unroll
    for (int i = 0; i < 4; ++i){
      int row0 = bm * 128 + wm * 64 + i * 16 + lg * 4;
      int b = row0 >> 11, s = row0 & 2047;
      #pragma unroll
      for (int j = 0; j < 4; ++j){
        int colseg = (bn & 7) * 128 + wn * 64 + j * 16 + lr;
        int h = colseg >> 6, dk = colseg & 63;
        ushort4 o4;
        o4.x = f2bf(acc[i][j][0]); o4.y = f2bf(acc[i][j][1]);
        o4.z = f2bf(acc[i][j][2]); o4.w = f2bf(acc[i][j][3]);
        *(ushort4*)&VhT[((size_t)(b * NH + h) * DK + dk) * SS + s] = o4;
      }
    }
  }
}

// ---------------- output projection GEMM (BM=64 for occupancy) ----------------
__global__ __launch_bounds__(256) void gemm_o64(const unsigned short* __restrict__ A,
                                                const unsigned short* __restrict__ Bt,
                                                float* __restrict__ O){
  __shared__ unsigned short Al[2][64 * 32];
  __shared__ unsigned short Bl[2][128 * 32];
  const int tid = threadIdx.x;
  const int wid = tid >> 6, lane = tid & 63;
  const int lr = lane & 15, lg = lane >> 4;
  const int wm = wid >> 1, wn = wid & 1;
  const int bm = blockIdx.x, bn = blockIdx.y;
  const int K = D_MODEL;

  f32x4 acc[2][4];
  #pragma unroll
  for (int i = 0; i < 2; ++i)
    #pragma unroll
    for (int j = 0; j < 4; ++j)
      acc[i][j] = (f32x4){0.f, 0.f, 0.f, 0.f};

  auto stage = [&](int buf, int kt){
    {
      int row = tid >> 2, c8 = (tid & 3) * 8;
      gload_lds16(A + (size_t)(bm * 64 + row) * K + kt * 32 + c8,
                  &Al[buf][wid << 9]);
    }
    #pragma unroll
    for (int r = 0; r < 2; ++r){
      int vt = tid + r * 256;
      int row = vt >> 2, c8 = (vt & 3) * 8;
      gload_lds16(Bt + (size_t)(bn * 128 + row) * K + kt * 32 + c8,
                  &Bl[buf][(wid << 9) + r * 2048]);
    }
  };

  stage(0, 0);
  int cur = 0;
  for (int kt = 0; kt < 32; ++kt){
    __syncthreads();
    if (kt + 1 < 32) stage(cur ^ 1, kt + 1);
    bf16x8 af[2], bfr[4];
    #pragma unroll
    for (int i = 0; i < 2; ++i)
      af[i] = *(const bf16x8*)&Al[cur][(wm * 32 + i * 16 + lr) * 32 + lg * 8];
    #pragma unroll
    for (int j = 0; j < 4; ++j)
      bfr[j] = *(const bf16x8*)&Bl[cur][(wn * 64 + j * 16 + lr) * 32 + lg * 8];
    #pragma unroll
    for (int i = 0; i < 2; ++i)
      #pragma unroll
      for (int j = 0; j < 4; ++j)
        acc[i][j] = __builtin_amdgcn_mfma_f32_16x16x32_bf16(af[i], bfr[j], acc[i][j], 0, 0, 0);
    cur ^= 1;
  }

  #pragma unroll
  for (int i = 0; i < 2; ++i){
    int row0 = bm * 64 + wm * 32 + i * 16 + lg * 4;
    #pragma unroll
    for (int j = 0; j < 4; ++j){
      int col = bn * 128 + wn * 64 + j * 16 + lr;
      #pragma unroll
      for (int p = 0; p < 4; ++p)
        O[(size_t)(row0 + p) * D_MODEL + col] = acc[i][j][p];
    }
  }
}

// ---------------- causal flash attention: 4-wave split-K + fold + LDS dbuf ----------------
// (round-12 proven kernel, 51.0 us) Grid (bh=32, px=16). Block processes
// qblk = px then 31-px (~17.5 rounds flat). m97 stage-ahead order:
// __syncthreads(); stage(next -> buf^1); compute(buf). 64 KB LDS dbuf.
__global__ __launch_bounds__(256) void attn_kernel(const unsigned short* __restrict__ Qh,
                                                   const unsigned short* __restrict__ Kh,
                                                   const unsigned short* __restrict__ VhT,
                                                   unsigned short* __restrict__ Oc){
  __shared__ unsigned short SL[2][4][4096];   // [buf][KA|VA|KB|VB][8KB], 64 KB
  const int bh = blockIdx.x;                  // bh%8 -> XCD stickiness
  const int px = blockIdx.y;                  // 0..15
  const int tid = threadIdx.x, wid = tid >> 6, lane = tid & 63;
  const int ln = lane & 31, hi = lane >> 5;
  const int qh = wid & 1, pp = wid >> 1;      // q-half, K-parity
  const int b = bh >> 4, h = bh & 15;
  const size_t kvbase = (size_t)bh * SS * DK;

  #pragma unroll 1
  for (int segq = 0; segq < 2; ++segq){
    const int qblk = segq ? (31 - px) : px;
    const int q0 = qblk * 64 + qh * 32;
    const int Tw = 2 * qblk + qh;             // wave's diagonal 32-key tile
    const int R = (qblk + 2) >> 1;            // rounds (pairs of 64-key tiles)

    const unsigned short* qp = Qh + kvbase + (size_t)(q0 + ln) * DK + hi * 8;
    bf16x8 qbv[4];
    #pragma unroll
    for (int c = 0; c < 4; ++c) qbv[c] = *(const bf16x8*)(qp + c * 16);

    f32x16 oa0 = {0,0,0,0,0,0,0,0,0,0,0,0,0,0,0,0};
    f32x16 oa1 = {0,0,0,0,0,0,0,0,0,0,0,0,0,0,0,0};
    float m = -1e30f, ls = 0.f;

    auto stage = [&](int bufb, int r){
      const int k0A = (2 * r) * 64;
      const int k0B = k0A + 64;
      const bool haveB = (2 * r + 1) <= qblk;
      #pragma unroll
      for (int i = 0; i < 2; ++i){
        const int c = i * 256 + tid;
        const int row = c >> 3;
        const int slot = (c & 7) ^ (row & 7);
        const int ldso = (i * 256 + wid * 64) * 8;   // shorts, wave-uniform
        gload_lds16(Kh  + kvbase + (size_t)(k0A + row) * DK + slot * 8, &SL[bufb][0][ldso]);
        gload_lds16(VhT + kvbase + (size_t)row * SS + k0A + slot * 8,   &SL[bufb][1][ldso]);
        if (haveB){
          gload_lds16(Kh  + kvbase + (size_t)(k0B + row) * DK + slot * 8, &SL[bufb][2][ldso]);
          gload_lds16(VhT + kvbase + (size_t)row * SS + k0B + slot * 8,   &SL[bufb][3][ldso]);
        }
      }
    };

    stage(0, 0);
    int cur = 0;
    #pragma unroll 1
    for (int r = 0; r < R; ++r){
      __syncthreads();                        // buf[cur] staged (vmcnt drained)
      if (r + 1 < R) stage(cur ^ 1, r + 1);   // next round's loads fly under compute

      const int t = 2 * r + pp;
      if (t <= qblk){
        const unsigned short* Kb = SL[cur][pp * 2];
        const unsigned short* Vb = SL[cur][pp * 2 + 1];

        // S^T (log2 domain) for key sub-tiles a/b of this 64-key tile
        f32x16 sta = {0,0,0,0,0,0,0,0,0,0,0,0,0,0,0,0};
        f32x16 stb = {0,0,0,0,0,0,0,0,0,0,0,0,0,0,0,0};
        __builtin_amdgcn_s_setprio(1);
        #pragma unroll
        for (int c = 0; c < 4; ++c){
          const int po = ((c * 2 + hi) ^ (ln & 7)) * 8;
          bf16x8 kfa = *(const bf16x8*)&Kb[ln * 64 + po];
          bf16x8 kfb = *(const bf16x8*)&Kb[(32 + ln) * 64 + po];
          sta = __builtin_amdgcn_mfma_f32_32x32x16_bf16(kfa, qbv[c], sta, 0, 0, 0);
          stb = __builtin_amdgcn_mfma_f32_32x32x16_bf16(kfb, qbv[c], stb, 0, 0, 0);
        }
        __builtin_amdgcn_s_setprio(0);

        // causal mask: 32-key tiles ta=2t, tb=2t+1 vs wave diag Tw
        const int ta = 2 * t, tb = 2 * t + 1;
        if (tb == Tw){
          #pragma unroll
          for (int rr = 0; rr < 16; ++rr){
            int kg = (rr & 3) + 8 * (rr >> 2) + 4 * hi;
            if (kg > ln) stb[rr] = -1e30f;
          }
        } else if (ta == Tw){
          #pragma unroll
          for (int rr = 0; rr < 16; ++rr){
            int kg = (rr & 3) + 8 * (rr >> 2) + 4 * hi;
            if (kg > ln) sta[rr] = -1e30f;
            stb[rr] = -1e30f;
          }
        }

        // tree max
        float tm[8];
        #pragma unroll
        for (int i = 0; i < 8; ++i)
          tm[i] = fmaxf(fmaxf(sta[2*i], sta[2*i+1]), fmaxf(stb[2*i], stb[2*i+1]));
        float mx = fmaxf(fmaxf(fmaxf(tm[0], tm[1]), fmaxf(tm[2], tm[3])),
                         fmaxf(fmaxf(tm[4], tm[5]), fmaxf(tm[6], tm[7])));
        mx = fmaxf(mx, __shfl_xor(mx, 32));

        // defer-max rescale
        if (__any(mx > m + DEFER_THR)){
          const float mn = fmaxf(m, mx);
          const float fac = __builtin_amdgcn_exp2f(m - mn);
          m = mn;
          ls *= fac;
          #pragma unroll
          for (int rr = 0; rr < 16; ++rr){ oa0[rr] *= fac; oa1[rr] *= fac; }
        }

        // P = exp2(st - m), tree sum
        #pragma unroll
        for (int rr = 0; rr < 16; ++rr){
          sta[rr] = __builtin_amdgcn_exp2f(sta[rr] - m);
          stb[rr] = __builtin_amdgcn_exp2f(stb[rr] - m);
        }
        float sm[8];
        #pragma unroll
        for (int i = 0; i < 8; ++i)
          sm[i] = (sta[2*i] + sta[2*i+1]) + (stb[2*i] + stb[2*i+1]);
        float rsum = ((sm[0] + sm[1]) + (sm[2] + sm[3])) + ((sm[4] + sm[5]) + (sm[6] + sm[7]));
        rsum += __shfl_xor(rsum, 32);
        ls += rsum;

        // P^T -> bf16 B-fragments
        u32 ca[8], cb[8];
        #pragma unroll
        for (int i = 0; i < 8; ++i){
          asm("v_cvt_pk_bf16_f32 %0, %1, %2" : "=v"(ca[i]) : "v"(sta[2*i]), "v"(sta[2*i+1]));
          asm("v_cvt_pk_bf16_f32 %0, %1, %2" : "=v"(cb[i]) : "v"(stb[2*i]), "v"(stb[2*i+1]));
        }
        u32 w0[4], w1[4], w2[4], w3[4];
        swap_half(ca[0], ca[2], hi, w0[0], w0[2]);
        swap_half(ca[1], ca[3], hi, w0[1], w0[3]);
        swap_half(ca[4], ca[6], hi, w1[0], w1[2]);
        swap_half(ca[5], ca[7], hi, w1[1], w1[3]);
        swap_half(cb[0], cb[2], hi, w2[0], w2[2]);
        swap_half(cb[1], cb[3], hi, w2[1], w2[3]);
        swap_half(cb[4], cb[6], hi, w3[0], w3[2]);
        swap_half(cb[5], cb[7], hi, w3[1], w3[3]);
        bf16x8 pf[4];
        __builtin_memcpy(&pf[0], w0, 16);
        __builtin_memcpy(&pf[1], w1, 16);
        __builtin_memcpy(&pf[2], w2, 16);
        __builtin_memcpy(&pf[3], w3, 16);

        // O^T += V^T * P^T
        __builtin_amdgcn_s_setprio(1);
        #pragma unroll
        for (int ks = 0; ks < 4; ++ks){
          const int po = ((ks * 2 + hi) ^ (ln & 7)) * 8;
          bf16x8 v0 = *(const bf16x8*)&Vb[ln * 64 + po];
          bf16x8 v1 = *(const bf16x8*)&Vb[(32 + ln) * 64 + po];
          oa0 = __builtin_amdgcn_mfma_f32_32x32x16_bf16(v0, pf[ks], oa0, 0, 0, 0);
          oa1 = __builtin_amdgcn_mfma_f32_32x32x16_bf16(v1, pf[ks], oa1, 0, 0, 0);
        }
        __builtin_amdgcn_s_setprio(0);
      }
      cur ^= 1;
    }
    __syncthreads();                          // last round's reads done before SL reuse

    // ---- 2-way split-K combine (exp2 domain), uses buffer set 0 ----
    float* oL  = (float*)&SL[0][0][0];        // [2][32][64] f32 = 16 KB
    float* mLs = (float*)&SL[0][2][0];        // mL[2][32] | lsL[2][32]
    if (wid >= 2){
      const int w = wid - 2;
      #pragma unroll
      for (int rr = 0; rr < 16; ++rr){
        oL[(w * 32 + rr) * 64 + lane]      = oa0[rr];
        oL[(w * 32 + 16 + rr) * 64 + lane] = oa1[rr];
      }
      if (hi == 0){ mLs[w * 32 + ln] = m; mLs[64 + w * 32 + ln] = ls; }
    }
    __syncthreads();
    if (wid < 2){
      const float m1  = mLs[wid * 32 + ln];
      const float ls1 = mLs[64 + wid * 32 + ln];
      const float mstar = fmaxf(m, m1);
      const float f0 = __builtin_amdgcn_exp2f(m  - mstar);
      const float f1 = __builtin_amdgcn_exp2f(m1 - mstar);
      const float inv = 1.0f / (f0 * ls + f1 * ls1);
      const size_t rowbase = ((size_t)b * SS + q0 + ln) * D_MODEL + h * DK;
      #pragma unroll
      for (int g = 0; g < 4; ++g){
        ushort4 o4;
        o4.x = f2bf((f0 * oa0[4*g + 0] + f1 * oL[(wid * 32 + 4*g + 0) * 64 + lane]) * inv);
        o4.y = f2bf((f0 * oa0[4*g + 1] + f1 * oL[(wid * 32 + 4*g + 1) * 64 + lane]) * inv);
        o4.z = f2bf((f0 * oa0[4*g + 2] + f1 * oL[(wid * 32 + 4*g + 2) * 64 + lane]) * inv);
        o4.w = f2bf((f0 * oa0[4*g + 3] + f1 * oL[(wid * 32 + 4*g + 3) * 64 + lane]) * inv);
        *(ushort4*)&Oc[rowbase + 8*g + 4*hi] = o4;
      }
      #pragma unroll
      for (int g = 0; g < 4; ++g){
        ushort4 o4;
        o4.x = f2bf((f0 * oa1[4*g + 0] + f1 * oL[(wid * 32 + 16 + 4*g + 0) * 64 + lane]) * inv);
        o4.y = f2bf((f0 * oa1[4*g + 1] + f1 * oL[(wid * 32 + 16 + 4*g + 1) * 64 + lane]) * inv);
        o4.z = f2bf((f0 * oa1[4*g + 2] + f1 * oL[(wid * 32 + 16 + 4*g + 2) * 64 + lane]) * inv);
        o4.w = f2bf((f0 * oa1[4*g + 3] + f1 * oL[(wid * 32 + 16 + 4*g + 3) * 64 + lane]) * inv);
        *(ushort4*)&Oc[rowbase + 32 + 8*g + 4*hi] = o4;
      }
    }
    __syncthreads();                          // combine reads done before next segment stages
  }
}

extern "C" void kernel_launch(void* const* d_in, const int* in_sizes, int n_in,
                              void* d_out, int out_size, void* d_ws, size_t ws_size,
                              hipStream_t stream){
  const float* q  = (const float*)d_in[0];
  const float* k  = (const float*)d_in[1];
  const float* v  = (const float*)d_in[2];
  // d_in[3]: causal mask (deterministic tril) — hardcoded in attn kernel
  const float* wq = (const float*)d_in[4];
  const float* wk = (const float*)d_in[5];
  const float* wv = (const float*)d_in[6];
  const float* wo = (const float*)d_in[7];
  float* out = (float*)d_out;

  char* ws = (char*)d_ws;
  const size_t MB = 1024 * 1024;
  unsigned short* WqkvT  = (unsigned short*)(ws + 0 * MB);    // 6 MB
  unsigned short* woT    = (unsigned short*)(ws + 6 * MB);    // 2 MB
  unsigned short* Qh     = (unsigned short*)(ws + 8 * MB);
  unsigned short* Kh     = (unsigned short*)(ws + 16 * MB);
  unsigned short* VhT    = (unsigned short*)(ws + 24 * MB);
  unsigned short* attnb  = (unsigned short*)(ws + 32 * MB);

  dim3 tg(16, 16, 4);
  transpose_cvt4<<<tg, 256, 0, stream>>>(wq, wk, wv, wo, WqkvT, woT);

  dim3 gqkv(M_TOT / 128, 3 * D_MODEL / 128);   // (32, 24) = 768 blocks
  gemm_qkv<<<gqkv, 256, 0, stream>>>(q, k, v, WqkvT, Qh, Kh, VhT);

  dim3 ga(BB * NH, SS / 128);                  // (32 bh, 16 px): folded pairs
  attn_kernel<<<ga, 256, 0, stream>>>(Qh, Kh, VhT, attnb);

  dim3 go(M_TOT / 64, D_MODEL / 128);          // (64, 8) = 512 blocks
  gemm_o64<<<go, 256, 0, stream>>>(attnb, woT, out);
}